// Round 2
// baseline (572.798 us; speedup 1.0000x reference)
//
#include <hip/hip_runtime.h>
#include <float.h>
#include <stdint.h>

// Problem constants
#define BB   128      // bs*t
#define CCH  256      // z channels
#define EMB_ 256      // embedding dim
#define HW   256      // h*w
#define NPIX 32768    // BB*HW
#define VOC  4096

typedef _Float16 f16x8 __attribute__((ext_vector_type(8)));
typedef float    f32x4 __attribute__((ext_vector_type(4)));

// async global->LDS, 16B per lane, dest = wave-uniform base + lane*16
__device__ __forceinline__ void async16(void* lds, const void* g) {
    __builtin_amdgcn_global_load_lds((const __attribute__((address_space(1))) uint32_t*)g,
                                     (__attribute__((address_space(3))) uint32_t*)lds,
                                     16, 0, 0);
}

// ---------------------------------------------------------------- K0a: c_sq
__global__ __launch_bounds__(256) void k_csq(const float* __restrict__ cb,
                                             float* __restrict__ csq) {
    int v = blockIdx.x * 256 + threadIdx.x;   // grid 16
    const float4* row = (const float4*)(cb + v * EMB_);
    float s = 0.f;
#pragma unroll 8
    for (int q = 0; q < 64; ++q) {
        float4 a = row[q];
        s = fmaf(a.x, a.x, fmaf(a.y, a.y, fmaf(a.z, a.z, fmaf(a.w, a.w, s))));
    }
    csq[v] = s;
}

// ------------------------------------------- K0b: postcode = post_b + W@cb^T
__global__ __launch_bounds__(256) void k_postcode(const float* __restrict__ cb,
                                                  const float* __restrict__ post_w,
                                                  const float* __restrict__ post_b,
                                                  float* __restrict__ postcode) {
    __shared__ float cbs[16][EMB_];           // 16 codebook rows, 16 KB
    int v0 = blockIdx.x * 16;                 // grid 256
    int c  = threadIdx.x;
#pragma unroll
    for (int r = 0; r < 16; ++r)
        cbs[r][c] = cb[(v0 + r) * EMB_ + c];  // coalesced
    __syncthreads();

    float acc[16];
    float bias = post_b[c];
#pragma unroll
    for (int r = 0; r < 16; ++r) acc[r] = bias;

    const float4* w4p = (const float4*)(post_w + c * EMB_);
    for (int e4 = 0; e4 < 64; ++e4) {
        float4 w4 = w4p[e4];
#pragma unroll
        for (int r = 0; r < 16; ++r) {
            float4 c4 = *(const float4*)&cbs[r][e4 * 4];
            acc[r] = fmaf(w4.x, c4.x, fmaf(w4.y, c4.y,
                     fmaf(w4.z, c4.z, fmaf(w4.w, c4.w, acc[r]))));
        }
    }
#pragma unroll
    for (int r = 0; r < 16; ++r)
        postcode[(v0 + r) * CCH + c] = acc[r];  // coalesced
}

// -------------------- K1: pre-conv -> z_out  (+ fused fp16 hi/lo A3 packing)
// z[b,e,hw] = pre_b[e] + sum_c pre_w[e,c]*(2x-1); then the exact same split
// math k_prep_z used: A3[pixg][kc8][row16][e8] = fp16 part of z*2^8
// (kc8<32: hi, else exact residual). Block covers exactly one pixg.
__global__ __launch_bounds__(256) void k_preconv(const float* __restrict__ x,
                                                 const float* __restrict__ pre_w,
                                                 const float* __restrict__ pre_b,
                                                 float* __restrict__ zout,
                                                 _Float16* __restrict__ A3) {
    __shared__ float xsT[16][260];            // [p][c], +4 pad kills conflicts
    __shared__ float zsf[256][17];            // [e][p] staged z for packing
    int b   = blockIdx.x >> 4;                // grid 2048
    int hw0 = (blockIdx.x & 15) * 16;
    int tid = threadIdx.x;
    int cg = tid >> 4, p = tid & 15;
#pragma unroll
    for (int it = 0; it < 16; ++it) {
        int c = it * 16 + cg;
        xsT[p][c] = 2.f * x[b * (CCH * HW) + c * HW + hw0 + p] - 1.f;
    }
    __syncthreads();

    int e = tid;
    float acc[16];
    float bias = pre_b[e];
#pragma unroll
    for (int q = 0; q < 16; ++q) acc[q] = bias;

    const float4* w4p = (const float4*)(pre_w + e * CCH);
    for (int c4 = 0; c4 < 64; ++c4) {
        float4 w4 = w4p[c4];
#pragma unroll
        for (int q = 0; q < 16; ++q) {
            float4 xv = *(const float4*)&xsT[q][c4 * 4];
            acc[q] = fmaf(w4.x, xv.x, fmaf(w4.y, xv.y,
                     fmaf(w4.z, xv.z, fmaf(w4.w, xv.w, acc[q]))));
        }
    }
    float* zo = zout + b * (EMB_ * HW) + e * HW + hw0;
#pragma unroll
    for (int q = 0; q < 4; ++q) {
        float4 s;
        s.x = acc[q * 4 + 0]; s.y = acc[q * 4 + 1];
        s.z = acc[q * 4 + 2]; s.w = acc[q * 4 + 3];
        *(float4*)&zo[q * 4] = s;
    }
    // ---- fused A3 pack (identical math to previous k_prep_z) ----
#pragma unroll
    for (int q = 0; q < 16; ++q) zsf[e][q] = acc[q];
    __syncthreads();
    int pixg = b * 16 + (hw0 >> 4);
#pragma unroll
    for (int it = 0; it < 4; ++it) {
        int c = it * 256 + tid;               // 1024 chunks of [row][8 elems]
        int kc8 = c >> 4, row = c & 15;
        int lo = kc8 >> 5;                    // 0: hi part, 1: lo part
        int kh = kc8 & 31;
        f16x8 outv;
#pragma unroll
        for (int j = 0; j < 8; ++j) {
            float v = zsf[kh * 8 + j][row] * 256.0f;    // exact 2^8 scale
            _Float16 h = (_Float16)v;                   // RN
            if (lo) h = (_Float16)(v - (float)h);       // exact residual, RN
            outv[j] = h;
        }
        *(f16x8*)(A3 + ((pixg * 64 + kc8) * 128 + row * 8)) = outv;
    }
}

// ---------------------------------------- K0c: split codebook into fp16 pack
// B3[vg(256)][kc8(64)][row16][e8], value = fp16 part of c*2^16.
__global__ __launch_bounds__(256) void k_prep_c(const float* __restrict__ cb,
                                                _Float16* __restrict__ B3) {
    __shared__ float cs[256][17];             // [e][vrow]
    int vg = blockIdx.x;                      // grid 256 (16 codes each)
    int t = threadIdx.x;
    int vr = t >> 4, e0 = (t & 15) << 4;
    const float* cp = cb + (vg * 16 + vr) * EMB_ + e0;
#pragma unroll
    for (int j = 0; j < 16; ++j)
        cs[e0 + j][vr] = cp[j];
    __syncthreads();
#pragma unroll
    for (int it = 0; it < 4; ++it) {
        int c = it * 256 + t;
        int kc8 = c >> 4, row = c & 15;
        int lo = kc8 >> 5;
        int kh = kc8 & 31;
        f16x8 outv;
#pragma unroll
        for (int j = 0; j < 8; ++j) {
            float v = cs[kh * 8 + j][row] * 65536.0f;   // exact 2^16 scale
            _Float16 h = (_Float16)v;
            if (lo) h = (_Float16)(v - (float)h);
            outv[j] = h;
        }
        *(f16x8*)(B3 + ((vg * 64 + kc8) * 128 + row * 8)) = outv;
    }
}

// --------- K2 staging helpers: chunk kc in [0,12): tau 0=zh*ch 1=zh*cl 2=zl*ch
__device__ __forceinline__ void issueA(const _Float16* __restrict__ A3, int bM,
                                       int w, int l4, int l15,
                                       _Float16* dst, int kcA) {
    int tau = kcA >> 2;
    int kA = ((tau == 2) ? 32 : 0) + (kcA & 3) * 8;   // zl half for lh term
#pragma unroll
    for (int i = 0; i < 2; ++i) {
        int q = w * 8 + i * 4 + l4;
        const _Float16* g = A3 + ((bM * 8 + (q >> 3)) * 64 + kA + (q & 7)) * 128 + l15 * 8;
        async16(dst + (w * 8 + i * 4) * 128, g);
    }
}

__device__ __forceinline__ void issueB(const _Float16* __restrict__ B3,
                                       int w, int l4, int l15,
                                       _Float16* dst, int vtB, int kcB) {
    int tau = kcB >> 2;
    int kB = ((tau == 1) ? 32 : 0) + (kcB & 3) * 8;   // cl half for hl term
#pragma unroll
    for (int i = 0; i < 4; ++i) {
        int q = w * 16 + i * 4 + l4;
        const _Float16* g = B3 + ((vtB * 16 + (q >> 3)) * 64 + kB + (q & 7)) * 128 + l15 * 8;
        async16(dst + (w * 16 + i * 4) * 128, g);
    }
}

// --------------------------------- K2: MFMA distance GEMM + fused argmin
// Same math/geometry as before (dot*2^24 = zh*ch + zh*cl + zl*ch, K=768,
// BM=128, BN=256, 8 waves 2Mx4N, wave 64x64). NEW: phase-split schedule with
// raw s_barrier + COUNTED vmcnt (T3+T4) + setprio around MFMA cluster (T5).
// A double-buffered (issued 1 chunk ahead), B triple-buffered (2 ahead);
// swap waits vmcnt(4) so the newest B-chunk's 4 loads stay in flight across
// every barrier. vmcnt(0) only at chunk 190 (tail).
__global__ __launch_bounds__(512) void k_dist(const float* __restrict__ zout,
                                              const _Float16* __restrict__ A3,
                                              const _Float16* __restrict__ B3,
                                              const float* __restrict__ csq,
                                              float* __restrict__ tok_f) {
    __shared__ __align__(16) _Float16 Ab[2][8192];    // 32 KB
    __shared__ __align__(16) _Float16 Bb[3][16384];   // 96 KB
    __shared__ float csq_s[VOC];                      // 16 KB
    __shared__ float zsq_s[128];
    __shared__ float red_b[8][64];
    __shared__ int   red_i[8][64];

    const int tid = threadIdx.x;
    const int l   = tid & 63;
    const int w   = tid >> 6;
    const int l15 = l & 15, l4 = l >> 4;
    const int wr  = w >> 2, wc = w & 3;
    const int bM  = blockIdx.x;               // grid 256, 128 pixels each

    // prologue staging: A(0)->Ab[0], B(0)->Bb[0], B(1)->Bb[1]
    issueA(A3, bM, w, l4, l15, Ab[0], 0);
    issueB(B3, w, l4, l15, Bb[0], 0, 0);
    issueB(B3, w, l4, l15, Bb[1], 0, 1);

    // csq -> LDS
#pragma unroll
    for (int i = 0; i < 8; ++i) csq_s[i * 512 + tid] = csq[i * 512 + tid];

    // zsq: serial fmaf chain over e (order identical to passing kernel)
    if (tid < 128) {
        const float* zp = zout + (bM >> 1) * (EMB_ * HW) + ((bM & 1) << 7) + tid;
        float s = 0.f;
        for (int k = 0; k < 256; ++k) { float zv = zp[k * HW]; s = fmaf(zv, zv, s); }
        zsq_s[tid] = s;
    }
    __syncthreads();   // full drain: Ab[0], Bb[0], Bb[1], csq_s, zsq_s valid

    float zq[16];
#pragma unroll
    for (int s = 0; s < 4; ++s)
#pragma unroll
        for (int r = 0; r < 4; ++r)
            zq[s * 4 + r] = zsq_s[(wr * 4 + s) * 16 + l4 * 4 + r];

    float best[16]; int bidx[16];
#pragma unroll
    for (int i = 0; i < 16; ++i) { best[i] = FLT_MAX; bidx[i] = 0; }

    const f32x4 zero4 = {0.f, 0.f, 0.f, 0.f};
    int bufA = 0, bufB = 0;
    for (int vt = 0; vt < 16; ++vt) {
        f32x4 acc[4][4];
#pragma unroll
        for (int s = 0; s < 4; ++s)
#pragma unroll
            for (int m = 0; m < 4; ++m) acc[s][m] = zero4;

        for (int kc = 0; kc < 12; ++kc) {
            const int n = vt * 12 + kc;
            int kc1 = kc + 1, vt1 = vt; if (kc1 == 12) { kc1 = 0; ++vt1; }
            int kc2 = kc + 2, vt2 = vt; if (kc2 >= 12) { kc2 -= 12; ++vt2; }

            // ---------------- phase 0 (k-step t=0) ----------------
            f16x8 a0[4], b0[4];
#pragma unroll
            for (int s = 0; s < 4; ++s)
                a0[s] = *(const f16x8*)&Ab[bufA][((wr * 4 + s) * 8 + l4) * 128 + l15 * 8];
#pragma unroll
            for (int m = 0; m < 4; ++m)
                b0[m] = *(const f16x8*)&Bb[bufB][((wc * 4 + m) * 8 + l4) * 128 + l15 * 8];
            if (vt1 < 16) issueA(A3, bM, w, l4, l15, Ab[bufA ^ 1], kc1);
            __builtin_amdgcn_s_barrier();
            asm volatile("s_waitcnt lgkmcnt(0)" ::: "memory");
            __builtin_amdgcn_sched_barrier(0);
            __builtin_amdgcn_s_setprio(1);
#pragma unroll
            for (int s = 0; s < 4; ++s)
#pragma unroll
                for (int m = 0; m < 4; ++m)
                    acc[s][m] = __builtin_amdgcn_mfma_f32_16x16x32_f16(a0[s], b0[m], acc[s][m], 0, 0, 0);
            __builtin_amdgcn_s_setprio(0);
            __builtin_amdgcn_s_barrier();

            // ---------------- phase 1 (k-step t=1) ----------------
            f16x8 a1[4], b1[4];
#pragma unroll
            for (int s = 0; s < 4; ++s)
                a1[s] = *(const f16x8*)&Ab[bufA][((wr * 4 + s) * 8 + 4 + l4) * 128 + l15 * 8];
#pragma unroll
            for (int m = 0; m < 4; ++m)
                b1[m] = *(const f16x8*)&Bb[bufB][((wc * 4 + m) * 8 + 4 + l4) * 128 + l15 * 8];
            if (vt2 < 16) {
                int dB = bufB + 2; if (dB >= 3) dB -= 3;
                issueB(B3, w, l4, l15, Bb[dB], vt2, kc2);
            }
            __builtin_amdgcn_s_barrier();
            asm volatile("s_waitcnt lgkmcnt(0)" ::: "memory");
            __builtin_amdgcn_sched_barrier(0);
            __builtin_amdgcn_s_setprio(1);
#pragma unroll
            for (int s = 0; s < 4; ++s)
#pragma unroll
                for (int m = 0; m < 4; ++m)
                    acc[s][m] = __builtin_amdgcn_mfma_f32_16x16x32_f16(a1[s], b1[m], acc[s][m], 0, 0, 0);
            __builtin_amdgcn_s_setprio(0);

            // ---------------- swap: counted drain, never 0 mid-loop ----
            // in-flight: B(n+1)x4 oldest, A(n+1)x2, B(n+2)x4 newest = 10.
            // vmcnt(4) retires B(n+1)+A(n+1); B(n+2) rides across barrier.
            if (n == 190) { asm volatile("s_waitcnt vmcnt(0)" ::: "memory"); }
            else          { asm volatile("s_waitcnt vmcnt(4)" ::: "memory"); }
            __builtin_amdgcn_s_barrier();
            __builtin_amdgcn_sched_barrier(0);
            bufA ^= 1;
            bufB = (bufB == 2) ? 0 : bufB + 1;
        }

        // ---- fold tile into running argmin (codes ascending within lane)
#pragma unroll
        for (int m = 0; m < 4; ++m) {
            int code = vt * 256 + (wc * 4 + m) * 16 + l15;
            float cs = csq_s[code];
#pragma unroll
            for (int s = 0; s < 4; ++s)
#pragma unroll
                for (int r = 0; r < 4; ++r) {
                    float dd = (zq[s * 4 + r] + cs) - acc[s][m][r] * 0x1p-23f;
                    int pi = s * 4 + r;
                    if (dd < best[pi]) { best[pi] = dd; bidx[pi] = code; }
                }
        }
    }

    // in-wave lexicographic reduce over the 16 code columns
#pragma unroll
    for (int off = 8; off >= 1; off >>= 1) {
#pragma unroll
        for (int i = 0; i < 16; ++i) {
            float ob = __shfl_xor(best[i], off, 64);
            int   oi = __shfl_xor(bidx[i], off, 64);
            if (ob < best[i] || (ob == best[i] && oi < bidx[i])) { best[i] = ob; bidx[i] = oi; }
        }
    }
    if (l15 == 0) {
#pragma unroll
        for (int s = 0; s < 4; ++s)
#pragma unroll
            for (int r = 0; r < 4; ++r) {
                int lp = s * 16 + l4 * 4 + r;             // wave-local pixel
                red_b[w][lp] = best[s * 4 + r];
                red_i[w][lp] = bidx[s * 4 + r];
            }
    }
    __syncthreads();
    // cross-wave (4 code-quarters) lexicographic combine + store tokens
    if (tid < 128) {
        int wrg = tid >> 6, lp = tid & 63;
        float bb = red_b[wrg * 4][lp]; int bi = red_i[wrg * 4][lp];
#pragma unroll
        for (int c = 1; c < 4; ++c) {
            float ob = red_b[wrg * 4 + c][lp]; int oi = red_i[wrg * 4 + c][lp];
            if (ob < bb || (ob == bb && oi < bi)) { bb = ob; bi = oi; }
        }
        tok_f[bM * 128 + wrg * 64 + lp] = (float)bi;
    }
}

// ------------------------- K3: gather zq_out = cb[t], recon = postcode[t]
__global__ __launch_bounds__(256) void k_gather(const float* __restrict__ tok_f,
                                                const float* __restrict__ cb,
                                                const float* __restrict__ postcode,
                                                float* __restrict__ zq_out,
                                                float* __restrict__ recon) {
    int b  = blockIdx.x >> 3;                 // grid 1024
    int e0 = (blockIdx.x & 7) * 32;
    int hw = threadIdx.x;
    int t  = (int)tok_f[b * HW + hw];
    const float* cbr = cb       + t * EMB_;
    const float* pcr = postcode + t * CCH;
    float* zq = zq_out + b * (EMB_ * HW) + hw;
    float* rc = recon  + b * (CCH * HW) + hw;
#pragma unroll
    for (int j = 0; j < 32; ++j) {
        int e = e0 + j;
        zq[e * HW] = cbr[e];                  // stores coalesced across hw
        rc[e * HW] = pcr[e];
    }
}

extern "C" void kernel_launch(void* const* d_in, const int* in_sizes, int n_in,
                              void* d_out, int out_size, void* d_ws, size_t ws_size,
                              hipStream_t stream) {
    const float* x      = (const float*)d_in[0];
    const float* cb     = (const float*)d_in[1];
    const float* pre_w  = (const float*)d_in[2];
    const float* pre_b  = (const float*)d_in[3];
    const float* post_w = (const float*)d_in[4];
    const float* post_b = (const float*)d_in[5];

    float* out    = (float*)d_out;
    float* z_out  = out;                       //  8388608 elems
    float* zq_out = out + 8388608;             //  8388608
    float* recon  = out + 16777216;            //  8388608
    float* tok_f  = out + 25165824;            //    32768

    // Scratch-in-output: A3 (33.55 MB) lives in zq_out, B3 (4 MB) in recon.
    // Both fully consumed by k_dist, then overwritten by k_gather.
    _Float16* A3 = (_Float16*)zq_out;          // [2048][64][16][8] fp16
    _Float16* B3 = (_Float16*)recon;           // [256][64][16][8]  fp16

    float* csq      = (float*)d_ws;            // 4096 floats
    float* postcode = csq + VOC;               // 4096*256 floats (4 MB)

    k_csq     <<<  16, 256, 0, stream>>>(cb, csq);
    k_postcode<<< 256, 256, 0, stream>>>(cb, post_w, post_b, postcode);
    k_prep_c  <<< 256, 256, 0, stream>>>(cb, B3);
    k_preconv <<<2048, 256, 0, stream>>>(x, pre_w, pre_b, z_out, A3);
    k_dist    <<< 256, 512, 0, stream>>>(z_out, A3, B3, csq, tok_f);
    k_gather  <<<1024, 256, 0, stream>>>(tok_f, cb, postcode, zq_out, recon);
}

// Round 3
// 547.998 us; speedup vs baseline: 1.0453x; 1.0453x over previous
//
#include <hip/hip_runtime.h>
#include <float.h>
#include <stdint.h>

// Problem constants
#define BB   128      // bs*t
#define CCH  256      // z channels
#define EMB_ 256      // embedding dim
#define HW   256      // h*w
#define NPIX 32768    // BB*HW
#define VOC  4096

typedef _Float16 f16x8 __attribute__((ext_vector_type(8)));
typedef float    f32x4 __attribute__((ext_vector_type(4)));

// async global->LDS, 16B per lane, dest = wave-uniform base + lane*16
__device__ __forceinline__ void async16(void* lds, const void* g) {
    __builtin_amdgcn_global_load_lds((const __attribute__((address_space(1))) uint32_t*)g,
                                     (__attribute__((address_space(3))) uint32_t*)lds,
                                     16, 0, 0);
}

// ---------------------------------------------------------------- K0a: c_sq
__global__ __launch_bounds__(256) void k_csq(const float* __restrict__ cb,
                                             float* __restrict__ csq) {
    int v = blockIdx.x * 256 + threadIdx.x;   // grid 16
    const float4* row = (const float4*)(cb + v * EMB_);
    float s = 0.f;
#pragma unroll 8
    for (int q = 0; q < 64; ++q) {
        float4 a = row[q];
        s = fmaf(a.x, a.x, fmaf(a.y, a.y, fmaf(a.z, a.z, fmaf(a.w, a.w, s))));
    }
    csq[v] = s;
}

// ------------------------------------------- K0b: postcode = post_b + W@cb^T
__global__ __launch_bounds__(256) void k_postcode(const float* __restrict__ cb,
                                                  const float* __restrict__ post_w,
                                                  const float* __restrict__ post_b,
                                                  float* __restrict__ postcode) {
    __shared__ float cbs[16][EMB_];           // 16 codebook rows, 16 KB
    int v0 = blockIdx.x * 16;                 // grid 256
    int c  = threadIdx.x;
#pragma unroll
    for (int r = 0; r < 16; ++r)
        cbs[r][c] = cb[(v0 + r) * EMB_ + c];  // coalesced
    __syncthreads();

    float acc[16];
    float bias = post_b[c];
#pragma unroll
    for (int r = 0; r < 16; ++r) acc[r] = bias;

    const float4* w4p = (const float4*)(post_w + c * EMB_);
    for (int e4 = 0; e4 < 64; ++e4) {
        float4 w4 = w4p[e4];
#pragma unroll
        for (int r = 0; r < 16; ++r) {
            float4 c4 = *(const float4*)&cbs[r][e4 * 4];
            acc[r] = fmaf(w4.x, c4.x, fmaf(w4.y, c4.y,
                     fmaf(w4.z, c4.z, fmaf(w4.w, c4.w, acc[r]))));
        }
    }
#pragma unroll
    for (int r = 0; r < 16; ++r)
        postcode[(v0 + r) * CCH + c] = acc[r];  // coalesced
}

// -------------------- K1: pre-conv -> z_out  (+ fused fp16 hi/lo A3 packing)
__global__ __launch_bounds__(256) void k_preconv(const float* __restrict__ x,
                                                 const float* __restrict__ pre_w,
                                                 const float* __restrict__ pre_b,
                                                 float* __restrict__ zout,
                                                 _Float16* __restrict__ A3) {
    __shared__ float xsT[16][260];            // [p][c], +4 pad kills conflicts
    __shared__ float zsf[256][17];            // [e][p] staged z for packing
    int b   = blockIdx.x >> 4;                // grid 2048
    int hw0 = (blockIdx.x & 15) * 16;
    int tid = threadIdx.x;
    int cg = tid >> 4, p = tid & 15;
#pragma unroll
    for (int it = 0; it < 16; ++it) {
        int c = it * 16 + cg;
        xsT[p][c] = 2.f * x[b * (CCH * HW) + c * HW + hw0 + p] - 1.f;
    }
    __syncthreads();

    int e = tid;
    float acc[16];
    float bias = pre_b[e];
#pragma unroll
    for (int q = 0; q < 16; ++q) acc[q] = bias;

    const float4* w4p = (const float4*)(pre_w + e * CCH);
    for (int c4 = 0; c4 < 64; ++c4) {
        float4 w4 = w4p[c4];
#pragma unroll
        for (int q = 0; q < 16; ++q) {
            float4 xv = *(const float4*)&xsT[q][c4 * 4];
            acc[q] = fmaf(w4.x, xv.x, fmaf(w4.y, xv.y,
                     fmaf(w4.z, xv.z, fmaf(w4.w, xv.w, acc[q]))));
        }
    }
    float* zo = zout + b * (EMB_ * HW) + e * HW + hw0;
#pragma unroll
    for (int q = 0; q < 4; ++q) {
        float4 s;
        s.x = acc[q * 4 + 0]; s.y = acc[q * 4 + 1];
        s.z = acc[q * 4 + 2]; s.w = acc[q * 4 + 3];
        *(float4*)&zo[q * 4] = s;
    }
    // ---- fused A3 pack (identical math to original k_prep_z) ----
#pragma unroll
    for (int q = 0; q < 16; ++q) zsf[e][q] = acc[q];
    __syncthreads();
    int pixg = b * 16 + (hw0 >> 4);
#pragma unroll
    for (int it = 0; it < 4; ++it) {
        int c = it * 256 + tid;               // 1024 chunks of [row][8 elems]
        int kc8 = c >> 4, row = c & 15;
        int lo = kc8 >> 5;                    // 0: hi part, 1: lo part
        int kh = kc8 & 31;
        f16x8 outv;
#pragma unroll
        for (int j = 0; j < 8; ++j) {
            float v = zsf[kh * 8 + j][row] * 256.0f;    // exact 2^8 scale
            _Float16 h = (_Float16)v;                   // RN
            if (lo) h = (_Float16)(v - (float)h);       // exact residual, RN
            outv[j] = h;
        }
        *(f16x8*)(A3 + ((pixg * 64 + kc8) * 128 + row * 8)) = outv;
    }
}

// ---------------------------------------- K0c: split codebook into fp16 pack
// B3[vg(256)][kc8(64)][row16][e8], value = fp16 part of c*2^16.
__global__ __launch_bounds__(256) void k_prep_c(const float* __restrict__ cb,
                                                _Float16* __restrict__ B3) {
    __shared__ float cs[256][17];             // [e][vrow]
    int vg = blockIdx.x;                      // grid 256 (16 codes each)
    int t = threadIdx.x;
    int vr = t >> 4, e0 = (t & 15) << 4;
    const float* cp = cb + (vg * 16 + vr) * EMB_ + e0;
#pragma unroll
    for (int j = 0; j < 16; ++j)
        cs[e0 + j][vr] = cp[j];
    __syncthreads();
#pragma unroll
    for (int it = 0; it < 4; ++it) {
        int c = it * 256 + t;
        int kc8 = c >> 4, row = c & 15;
        int lo = kc8 >> 5;
        int kh = kc8 & 31;
        f16x8 outv;
#pragma unroll
        for (int j = 0; j < 8; ++j) {
            float v = cs[kh * 8 + j][row] * 65536.0f;   // exact 2^16 scale
            _Float16 h = (_Float16)v;
            if (lo) h = (_Float16)(v - (float)h);
            outv[j] = h;
        }
        *(f16x8*)(B3 + ((vg * 64 + kc8) * 128 + row * 8)) = outv;
    }
}

// --------- K2 staging: chunk kc in [0,12): tau 0=zh*ch 1=zh*cl 2=zl*ch
// Each wave stages 2 fragment-groups (4 KB) of A and of B per chunk.
__device__ __forceinline__ void issueA(const _Float16* __restrict__ A3, int bM,
                                       int w, int l4, int l15,
                                       _Float16* dst, int kcA) {
    int tau = kcA >> 2;
    int kA = ((tau == 2) ? 32 : 0) + (kcA & 3) * 8;   // zl half for lh term
#pragma unroll
    for (int i = 0; i < 4; ++i) {
        int pg = 2 * w + (i >> 1);                    // pixel-group 0..15
        int kq = (i & 1) * 4;
        const _Float16* g = A3 + (((bM * 16 + pg) * 64) + kA + kq + l4) * 128 + l15 * 8;
        async16(dst + (pg * 8 + kq) * 128, g);
    }
}

__device__ __forceinline__ void issueB(const _Float16* __restrict__ B3, int vgbase,
                                       int w, int l4, int l15,
                                       _Float16* dst, int kcB) {
    int tau = kcB >> 2;
    int kB = ((tau == 1) ? 32 : 0) + (kcB & 3) * 8;   // cl half for hl term
#pragma unroll
    for (int i = 0; i < 4; ++i) {
        int vg = 2 * w + (i >> 1);                    // code-group 0..15
        int kq = (i & 1) * 4;
        const _Float16* g = B3 + (((vgbase + vg) * 64) + kB + kq + l4) * 128 + l15 * 8;
        async16(dst + (vg * 8 + kq) * 128, g);
    }
}

// --------------------------------- K2: MFMA distance GEMM + fused argmin
// 256x256 acc tile (m201 geometry), BK=64, 8 waves (2M x 4N), wave=128x64.
// Grid = 128 M-tiles x 2 code-halves; per block 8 vt of 256 codes.
// R1's proven minimum-2-phase schedule: issue next chunk -> compute current
// -> ONE __syncthreads per chunk. Per-(pixel,code) MFMA chain identical to
// the passing R1 kernel (same 24-instr k-order) -> tokens bit-identical.
__global__ __launch_bounds__(512) void k_dist(const float* __restrict__ zout,
                                              const _Float16* __restrict__ A3,
                                              const _Float16* __restrict__ B3,
                                              const float* __restrict__ csq,
                                              float* __restrict__ bestw,
                                              int* __restrict__ bidxw) {
    __shared__ __align__(16) _Float16 Ab[2][16384];   // 64 KB
    __shared__ __align__(16) _Float16 Bb[2][16384];   // 64 KB
    __shared__ float csq_s[2048];                     // 8 KB (this half only)
    __shared__ float zsq_s[256];
    __shared__ float red_b[8][128];
    __shared__ int   red_i[8][128];

    const int tid = threadIdx.x;
    const int l   = tid & 63;
    const int w   = tid >> 6;
    const int l15 = l & 15, l4 = l >> 4;
    const int wr  = w >> 2, wc = w & 3;               // 2M x 4N wave grid
    const int bM  = blockIdx.x & 127;                 // M-tile: 256 pixels = image bM
    const int nh  = blockIdx.x >> 7;                  // code half 0/1

    // prologue staging: chunk (vt=0,kc=0) into buffer 0 (overlaps zsq below)
    issueA(A3, bM, w, l4, l15, Ab[0], 0);
    issueB(B3, nh * 128, w, l4, l15, Bb[0], 0);

    // csq half -> LDS
#pragma unroll
    for (int j = 0; j < 4; ++j) csq_s[j * 512 + tid] = csq[nh * 2048 + j * 512 + tid];

    // zsq: serial fmaf chain over e (identical rounding to passing kernel)
    if (tid < 256) {
        const float* zp = zout + bM * (EMB_ * HW) + tid;
        float s = 0.f;
        for (int k = 0; k < 256; ++k) { float zv = zp[k * HW]; s = fmaf(zv, zv, s); }
        zsq_s[tid] = s;
    }
    __syncthreads();   // drains prologue loads; csq_s/zsq_s valid

    float best[32]; int bidx[32];
#pragma unroll
    for (int i = 0; i < 32; ++i) { best[i] = FLT_MAX; bidx[i] = 0; }

    const f32x4 zero4 = {0.f, 0.f, 0.f, 0.f};
    int buf = 0;
    for (int vt = 0; vt < 8; ++vt) {
        f32x4 acc[8][4];
#pragma unroll
        for (int s = 0; s < 8; ++s)
#pragma unroll
            for (int n = 0; n < 4; ++n) acc[s][n] = zero4;

        for (int kc = 0; kc < 12; ++kc) {
            // ---- issue next chunk into buf^1 (overlaps this chunk's compute)
            int nkc = kc + 1, nvt = vt;
            if (nkc == 12) { nkc = 0; ++nvt; }
            if (nvt < 8) {
                issueA(A3, bM, w, l4, l15, Ab[buf ^ 1], nkc);
                issueB(B3, nh * 128 + nvt * 16, w, l4, l15, Bb[buf ^ 1], nkc);
            }
            // ---- compute current chunk (2 k-steps of K=32)
#pragma unroll
            for (int t = 0; t < 2; ++t) {
                f16x8 af[8], bf[4];
#pragma unroll
                for (int s = 0; s < 8; ++s)
                    af[s] = *(const f16x8*)&Ab[buf][((wr * 8 + s) * 8 + t * 4 + l4) * 128 + l15 * 8];
#pragma unroll
                for (int n = 0; n < 4; ++n)
                    bf[n] = *(const f16x8*)&Bb[buf][((wc * 4 + n) * 8 + t * 4 + l4) * 128 + l15 * 8];
#pragma unroll
                for (int s = 0; s < 8; ++s)
#pragma unroll
                    for (int n = 0; n < 4; ++n)
                        acc[s][n] = __builtin_amdgcn_mfma_f32_16x16x32_f16(af[s], bf[n], acc[s][n], 0, 0, 0);
            }
            __syncthreads();                  // buf consumed; buf^1 staged
            buf ^= 1;
        }

        // ---- fold tile into running argmin (codes ascending per slot)
#pragma unroll
        for (int n = 0; n < 4; ++n) {
            int cl = vt * 256 + (wc * 4 + n) * 16 + l15;   // half-local code
            float cs = csq_s[cl];
            int code = nh * 2048 + cl;
#pragma unroll
            for (int s = 0; s < 8; ++s)
#pragma unroll
                for (int r = 0; r < 4; ++r) {
                    float dd = (zsq_s[wr * 128 + s * 16 + l4 * 4 + r] + cs)
                               - acc[s][n][r] * 0x1p-23f;
                    int pi = s * 4 + r;
                    if (dd < best[pi]) { best[pi] = dd; bidx[pi] = code; }
                }
        }
    }

    // reduce over the 16 code-columns (l15 dimension) lexicographically
#pragma unroll
    for (int off = 8; off >= 1; off >>= 1) {
#pragma unroll
        for (int i = 0; i < 32; ++i) {
            float ob = __shfl_xor(best[i], off, 64);
            int   oi = __shfl_xor(bidx[i], off, 64);
            if (ob < best[i] || (ob == best[i] && oi < bidx[i])) { best[i] = ob; bidx[i] = oi; }
        }
    }
    if (l15 == 0) {
#pragma unroll
        for (int s = 0; s < 8; ++s)
#pragma unroll
            for (int r = 0; r < 4; ++r) {
                int pl = s * 16 + l4 * 4 + r;             // wave-local pixel
                red_b[w][pl] = best[s * 4 + r];
                red_i[w][pl] = bidx[s * 4 + r];
            }
    }
    __syncthreads();
    // combine the 4 code-quarter waves (same wr) per pixel, store (best,idx)
    if (tid < 256) {
        int wrg = tid >> 7, pl = tid & 127;
        float bb = red_b[wrg * 4][pl]; int bi = red_i[wrg * 4][pl];
#pragma unroll
        for (int c = 1; c < 4; ++c) {
            float ob = red_b[wrg * 4 + c][pl]; int oi = red_i[wrg * 4 + c][pl];
            if (ob < bb || (ob == bb && oi < bi)) { bb = ob; bi = oi; }
        }
        bestw[nh * NPIX + bM * 256 + tid] = bb;
        bidxw[nh * NPIX + bM * 256 + tid] = bi;
    }
}

// ---------------- K2b: combine the two code-halves into final tokens
__global__ __launch_bounds__(256) void k_argmin2(const float* __restrict__ bestw,
                                                 const int* __restrict__ bidxw,
                                                 float* __restrict__ tok_f) {
    int i = blockIdx.x * 256 + threadIdx.x;   // grid 128
    float b0 = bestw[i], b1 = bestw[NPIX + i];
    int   i0 = bidxw[i], i1 = bidxw[NPIX + i];
    // half-0 indices are always lower -> ties go to i0
    tok_f[i] = (float)((b1 < b0) ? i1 : i0);
}

// ------------------------- K3: gather zq_out = cb[t], recon = postcode[t]
__global__ __launch_bounds__(256) void k_gather(const float* __restrict__ tok_f,
                                                const float* __restrict__ cb,
                                                const float* __restrict__ postcode,
                                                float* __restrict__ zq_out,
                                                float* __restrict__ recon) {
    int b  = blockIdx.x >> 3;                 // grid 1024
    int e0 = (blockIdx.x & 7) * 32;
    int hw = threadIdx.x;
    int t  = (int)tok_f[b * HW + hw];
    const float* cbr = cb       + t * EMB_;
    const float* pcr = postcode + t * CCH;
    float* zq = zq_out + b * (EMB_ * HW) + hw;
    float* rc = recon  + b * (CCH * HW) + hw;
#pragma unroll
    for (int j = 0; j < 32; ++j) {
        int e = e0 + j;
        zq[e * HW] = cbr[e];                  // stores coalesced across hw
        rc[e * HW] = pcr[e];
    }
}

extern "C" void kernel_launch(void* const* d_in, const int* in_sizes, int n_in,
                              void* d_out, int out_size, void* d_ws, size_t ws_size,
                              hipStream_t stream) {
    const float* x      = (const float*)d_in[0];
    const float* cb     = (const float*)d_in[1];
    const float* pre_w  = (const float*)d_in[2];
    const float* pre_b  = (const float*)d_in[3];
    const float* post_w = (const float*)d_in[4];
    const float* post_b = (const float*)d_in[5];

    float* out    = (float*)d_out;
    float* z_out  = out;                       //  8388608 elems
    float* zq_out = out + 8388608;             //  8388608
    float* recon  = out + 16777216;            //  8388608
    float* tok_f  = out + 25165824;            //    32768

    // Scratch-in-output: A3 (33.55 MB) fills zq_out exactly; B3 (4 MB) +
    // best/bidx scratch live in recon. All consumed before k_gather writes.
    _Float16* A3 = (_Float16*)zq_out;          // [2048][64][16][8] fp16
    _Float16* B3 = (_Float16*)recon;           // [256][64][16][8]  fp16
    float* bestw = recon + 1048576;            // 2*32768 floats
    int*   bidxw = (int*)(recon + 1048576 + 2 * NPIX);

    float* csq      = (float*)d_ws;            // 4096 floats
    float* postcode = csq + VOC;               // 4096*256 floats (4 MB)

    k_csq     <<<  16, 256, 0, stream>>>(cb, csq);
    k_postcode<<< 256, 256, 0, stream>>>(cb, post_w, post_b, postcode);
    k_prep_c  <<< 256, 256, 0, stream>>>(cb, B3);
    k_preconv <<<2048, 256, 0, stream>>>(x, pre_w, pre_b, z_out, A3);
    k_dist    <<< 256, 512, 0, stream>>>(z_out, A3, B3, csq, bestw, bidxw);
    k_argmin2 <<< 128, 256, 0, stream>>>(bestw, bidxw, tok_f);
    k_gather  <<<1024, 256, 0, stream>>>(tok_f, cb, postcode, zq_out, recon);
}

// Round 4
// 496.026 us; speedup vs baseline: 1.1548x; 1.1048x over previous
//
#include <hip/hip_runtime.h>
#include <float.h>
#include <stdint.h>

// Problem constants
#define BB   128      // bs*t
#define CCH  256      // z channels
#define EMB_ 256      // embedding dim
#define HW   256      // h*w
#define NPIX 32768    // BB*HW
#define VOC  4096

typedef _Float16 f16x8 __attribute__((ext_vector_type(8)));
typedef float    f32x4 __attribute__((ext_vector_type(4)));

// async global->LDS, 16B per lane, dest = wave-uniform base + lane*16
__device__ __forceinline__ void async16(void* lds, const void* g) {
    __builtin_amdgcn_global_load_lds((const __attribute__((address_space(1))) uint32_t*)g,
                                     (__attribute__((address_space(3))) uint32_t*)lds,
                                     16, 0, 0);
}

// ---------------------------------------------------------------- K0a: c_sq
__global__ __launch_bounds__(256) void k_csq(const float* __restrict__ cb,
                                             float* __restrict__ csq) {
    int v = blockIdx.x * 256 + threadIdx.x;   // grid 16
    const float4* row = (const float4*)(cb + v * EMB_);
    float s = 0.f;
#pragma unroll 8
    for (int q = 0; q < 64; ++q) {
        float4 a = row[q];
        s = fmaf(a.x, a.x, fmaf(a.y, a.y, fmaf(a.z, a.z, fmaf(a.w, a.w, s))));
    }
    csq[v] = s;
}

// ------------------------------------------- K0b: postcode = post_b + W@cb^T
__global__ __launch_bounds__(256) void k_postcode(const float* __restrict__ cb,
                                                  const float* __restrict__ post_w,
                                                  const float* __restrict__ post_b,
                                                  float* __restrict__ postcode) {
    __shared__ float cbs[16][EMB_];           // 16 codebook rows, 16 KB
    int v0 = blockIdx.x * 16;                 // grid 256
    int c  = threadIdx.x;
#pragma unroll
    for (int r = 0; r < 16; ++r)
        cbs[r][c] = cb[(v0 + r) * EMB_ + c];  // coalesced
    __syncthreads();

    float acc[16];
    float bias = post_b[c];
#pragma unroll
    for (int r = 0; r < 16; ++r) acc[r] = bias;

    const float4* w4p = (const float4*)(post_w + c * EMB_);
    for (int e4 = 0; e4 < 64; ++e4) {
        float4 w4 = w4p[e4];
#pragma unroll
        for (int r = 0; r < 16; ++r) {
            float4 c4 = *(const float4*)&cbs[r][e4 * 4];
            acc[r] = fmaf(w4.x, c4.x, fmaf(w4.y, c4.y,
                     fmaf(w4.z, c4.z, fmaf(w4.w, c4.w, acc[r]))));
        }
    }
#pragma unroll
    for (int r = 0; r < 16; ++r)
        postcode[(v0 + r) * CCH + c] = acc[r];  // coalesced
}

// -------------------- K1: pre-conv -> z_out  (+ fused fp16 hi/lo A3 packing)
__global__ __launch_bounds__(256) void k_preconv(const float* __restrict__ x,
                                                 const float* __restrict__ pre_w,
                                                 const float* __restrict__ pre_b,
                                                 float* __restrict__ zout,
                                                 _Float16* __restrict__ A3) {
    __shared__ float xsT[16][260];            // [p][c], +4 pad kills conflicts
    __shared__ float zsf[256][17];            // [e][p] staged z for packing
    int b   = blockIdx.x >> 4;                // grid 2048
    int hw0 = (blockIdx.x & 15) * 16;
    int tid = threadIdx.x;
    int cg = tid >> 4, p = tid & 15;
#pragma unroll
    for (int it = 0; it < 16; ++it) {
        int c = it * 16 + cg;
        xsT[p][c] = 2.f * x[b * (CCH * HW) + c * HW + hw0 + p] - 1.f;
    }
    __syncthreads();

    int e = tid;
    float acc[16];
    float bias = pre_b[e];
#pragma unroll
    for (int q = 0; q < 16; ++q) acc[q] = bias;

    const float4* w4p = (const float4*)(pre_w + e * CCH);
    for (int c4 = 0; c4 < 64; ++c4) {
        float4 w4 = w4p[c4];
#pragma unroll
        for (int q = 0; q < 16; ++q) {
            float4 xv = *(const float4*)&xsT[q][c4 * 4];
            acc[q] = fmaf(w4.x, xv.x, fmaf(w4.y, xv.y,
                     fmaf(w4.z, xv.z, fmaf(w4.w, xv.w, acc[q]))));
        }
    }
    float* zo = zout + b * (EMB_ * HW) + e * HW + hw0;
#pragma unroll
    for (int q = 0; q < 4; ++q) {
        float4 s;
        s.x = acc[q * 4 + 0]; s.y = acc[q * 4 + 1];
        s.z = acc[q * 4 + 2]; s.w = acc[q * 4 + 3];
        *(float4*)&zo[q * 4] = s;
    }
    // ---- fused A3 pack (identical math to original k_prep_z) ----
#pragma unroll
    for (int q = 0; q < 16; ++q) zsf[e][q] = acc[q];
    __syncthreads();
    int pixg = b * 16 + (hw0 >> 4);
#pragma unroll
    for (int it = 0; it < 4; ++it) {
        int c = it * 256 + tid;               // 1024 chunks of [row][8 elems]
        int kc8 = c >> 4, row = c & 15;
        int lo = kc8 >> 5;                    // 0: hi part, 1: lo part
        int kh = kc8 & 31;
        f16x8 outv;
#pragma unroll
        for (int j = 0; j < 8; ++j) {
            float v = zsf[kh * 8 + j][row] * 256.0f;    // exact 2^8 scale
            _Float16 h = (_Float16)v;                   // RN
            if (lo) h = (_Float16)(v - (float)h);       // exact residual, RN
            outv[j] = h;
        }
        *(f16x8*)(A3 + ((pixg * 64 + kc8) * 128 + row * 8)) = outv;
    }
}

// ---------------------------------------- K0c: split codebook into fp16 pack
// B3[vg(256)][kc8(64)][row16][e8], value = fp16 part of c*2^16.
__global__ __launch_bounds__(256) void k_prep_c(const float* __restrict__ cb,
                                                _Float16* __restrict__ B3) {
    __shared__ float cs[256][17];             // [e][vrow]
    int vg = blockIdx.x;                      // grid 256 (16 codes each)
    int t = threadIdx.x;
    int vr = t >> 4, e0 = (t & 15) << 4;
    const float* cp = cb + (vg * 16 + vr) * EMB_ + e0;
#pragma unroll
    for (int j = 0; j < 16; ++j)
        cs[e0 + j][vr] = cp[j];
    __syncthreads();
#pragma unroll
    for (int it = 0; it < 4; ++it) {
        int c = it * 256 + t;
        int kc8 = c >> 4, row = c & 15;
        int lo = kc8 >> 5;
        int kh = kc8 & 31;
        f16x8 outv;
#pragma unroll
        for (int j = 0; j < 8; ++j) {
            float v = cs[kh * 8 + j][row] * 65536.0f;   // exact 2^16 scale
            _Float16 h = (_Float16)v;
            if (lo) h = (_Float16)(v - (float)h);
            outv[j] = h;
        }
        *(f16x8*)(B3 + ((vg * 64 + kc8) * 128 + row * 8)) = outv;
    }
}

// --------- K2 staging: BK=32 chunk = 4 contiguous kc8 units at offset kA/kB.
// Chunk kc in [0,24): tau = kc>>3 (0: zh*ch, 1: zh*cl, 2: zl*ch).
// Per call each wave stages 2 pixel/code-groups (16 KB total per operand).
__device__ __forceinline__ void issueA(const _Float16* __restrict__ A3, int bM,
                                       int w, int l, _Float16* dst, int kA) {
#pragma unroll
    for (int i = 0; i < 2; ++i) {
        int pg = 2 * w + i;                           // pixel-group 0..15
        const _Float16* g = A3 + ((bM * 16 + pg) * 64 + kA) * 128 + l * 8;
        async16(dst + pg * 512, g);                   // linear both sides
    }
}

__device__ __forceinline__ void issueB(const _Float16* __restrict__ B3, int vgbase,
                                       int w, int l, _Float16* dst, int kB) {
#pragma unroll
    for (int i = 0; i < 2; ++i) {
        int vg = 2 * w + i;                           // code-group 0..15
        const _Float16* g = B3 + ((vgbase + vg) * 64 + kB) * 128 + l * 8;
        async16(dst + vg * 512, g);
    }
}

// --------------------------------- K2: MFMA distance GEMM + fused argmin
// 256x256 acc tile, BK=32, 8 waves (2M x 4N), wave = 128x64.
// TRUE fine-grained phase schedule (m201 template port): per chunk 2 phases,
// each {ds_read 4 frags || issue 2 async16 of chunk n+2 -> s_barrier ->
// lgkmcnt(0)+sched_barrier -> setprio(1) 16 MFMA setprio(0) -> s_barrier}.
// Triple-buffered LDS, depth-2 prefetch, COUNTED vmcnt(4) per chunk end
// (vmcnt(0) only at chunk 190). Per-(pixel,code) MFMA k-order identical to
// the passing R1/R3 kernels -> tokens bit-identical.
__global__ __launch_bounds__(512) void k_dist(const float* __restrict__ zout,
                                              const _Float16* __restrict__ A3,
                                              const _Float16* __restrict__ B3,
                                              const float* __restrict__ csq,
                                              float* __restrict__ bestw,
                                              int* __restrict__ bidxw) {
    __shared__ __align__(16) _Float16 Ab[3][8192];    // 48 KB (16 KB/chunk)
    __shared__ __align__(16) _Float16 Bb[3][8192];    // 48 KB
    __shared__ float csq_s[2048];                     // 8 KB (this half only)
    __shared__ float zsq_s[256];
    __shared__ float red_b[8][128];
    __shared__ int   red_i[8][128];

    const int tid = threadIdx.x;
    const int l   = tid & 63;
    const int w   = tid >> 6;
    const int l15 = l & 15, l4 = l >> 4;
    const int wr  = w >> 2, wc = w & 3;               // 2M x 4N wave grid
    const int bM  = blockIdx.x & 127;                 // M-tile (256 pixels)
    const int nh  = blockIdx.x >> 7;                  // code half 0/1
    const int vgb = nh * 128;                         // B3 group base

    // k-offsets (kc8 units) for chunk kc: A uses zl-half for term 2 (lh),
    // B uses cl-half for term 1 (hl).
    // kA(kc) = (kc>=16 ? 32:0) + (kc&7)*4 ; kB(kc) = (kc>=8 && kc<16 ? 32:0) + (kc&7)*4

    // prologue: stage chunks 0 and 1
    issueA(A3, bM, w, l, Ab[0], 0);
    issueB(B3, vgb, w, l, Bb[0], 0);
    issueA(A3, bM, w, l, Ab[1], 4);
    issueB(B3, vgb, w, l, Bb[1], 4);

    // csq half -> LDS
#pragma unroll
    for (int j = 0; j < 4; ++j) csq_s[j * 512 + tid] = csq[nh * 2048 + j * 512 + tid];

    // zsq: serial fmaf chain over e (identical rounding to passing kernel)
    if (tid < 256) {
        const float* zp = zout + bM * (EMB_ * HW) + tid;
        float s = 0.f;
        for (int k = 0; k < 256; ++k) { float zv = zp[k * HW]; s = fmaf(zv, zv, s); }
        zsq_s[tid] = s;
    }
    __syncthreads();   // one-time full drain: chunks 0,1 + csq_s + zsq_s ready

    float best[32]; int bidx[32];
#pragma unroll
    for (int i = 0; i < 32; ++i) { best[i] = FLT_MAX; bidx[i] = 0; }

    const f32x4 zero4 = {0.f, 0.f, 0.f, 0.f};
    int cur = 0;
    for (int vt = 0; vt < 8; ++vt) {
        f32x4 acc[8][4];
#pragma unroll
        for (int s = 0; s < 8; ++s)
#pragma unroll
            for (int m = 0; m < 4; ++m) acc[s][m] = zero4;

        for (int kc = 0; kc < 24; ++kc) {
            const int n = vt * 24 + kc;               // global chunk 0..191
            int kc2 = kc + 2, vt2 = vt;
            if (kc2 >= 24) { kc2 -= 24; ++vt2; }
            const int nxt = (cur + 2 >= 3) ? cur - 1 : cur + 2;
            const bool pf = (vt2 < 8);
            const int kA2 = ((kc2 >= 16) ? 32 : 0) + (kc2 & 7) * 4;
            const int kB2 = ((kc2 >= 8 && kc2 < 16) ? 32 : 0) + (kc2 & 7) * 4;

            // ---------------- phase 0: s-half 0 ----------------
            f16x8 af0[4], bf[4];
#pragma unroll
            for (int s = 0; s < 4; ++s)
                af0[s] = *(const f16x8*)&Ab[cur][(wr * 8 + s) * 512 + l4 * 128 + l15 * 8];
#pragma unroll
            for (int m = 0; m < 4; ++m)
                bf[m] = *(const f16x8*)&Bb[cur][(wc * 4 + m) * 512 + l4 * 128 + l15 * 8];
            if (pf) issueA(A3, bM, w, l, Ab[nxt], kA2);
            __builtin_amdgcn_s_barrier();
            asm volatile("s_waitcnt lgkmcnt(0)" ::: "memory");
            __builtin_amdgcn_sched_barrier(0);
            __builtin_amdgcn_s_setprio(1);
#pragma unroll
            for (int s = 0; s < 4; ++s)
#pragma unroll
                for (int m = 0; m < 4; ++m)
                    acc[s][m] = __builtin_amdgcn_mfma_f32_16x16x32_f16(af0[s], bf[m], acc[s][m], 0, 0, 0);
            __builtin_amdgcn_s_setprio(0);
            __builtin_amdgcn_s_barrier();

            // ---------------- phase 1: s-half 1 ----------------
            f16x8 af1[4];
#pragma unroll
            for (int s = 0; s < 4; ++s)
                af1[s] = *(const f16x8*)&Ab[cur][(wr * 8 + 4 + s) * 512 + l4 * 128 + l15 * 8];
            if (pf) issueB(B3, vgb + vt2 * 16, w, l, Bb[nxt], kB2);
            __builtin_amdgcn_s_barrier();
            asm volatile("s_waitcnt lgkmcnt(0)" ::: "memory");
            __builtin_amdgcn_sched_barrier(0);
            __builtin_amdgcn_s_setprio(1);
#pragma unroll
            for (int s = 0; s < 4; ++s)
#pragma unroll
                for (int m = 0; m < 4; ++m)
                    acc[4 + s][m] = __builtin_amdgcn_mfma_f32_16x16x32_f16(af1[s], bf[m], acc[4 + s][m], 0, 0, 0);
            __builtin_amdgcn_s_setprio(0);
            // counted drain: chunk n+1 must be in LDS; chunk n+2 stays in flight
            if (n == 190) { asm volatile("s_waitcnt vmcnt(0)" ::: "memory"); }
            else          { asm volatile("s_waitcnt vmcnt(4)" ::: "memory"); }
            __builtin_amdgcn_s_barrier();
            __builtin_amdgcn_sched_barrier(0);
            cur = (cur + 1 >= 3) ? 0 : cur + 1;
        }

        // ---- fold tile into running argmin (codes ascending per slot)
#pragma unroll
        for (int m = 0; m < 4; ++m) {
            int cl = vt * 256 + (wc * 4 + m) * 16 + l15;   // half-local code
            float cs = csq_s[cl];
            int code = nh * 2048 + cl;
#pragma unroll
            for (int s = 0; s < 8; ++s)
#pragma unroll
                for (int r = 0; r < 4; ++r) {
                    float dd = (zsq_s[wr * 128 + s * 16 + l4 * 4 + r] + cs)
                               - acc[s][m][r] * 0x1p-23f;
                    int pi = s * 4 + r;
                    if (dd < best[pi]) { best[pi] = dd; bidx[pi] = code; }
                }
        }
    }

    // reduce over the 16 code-columns (l15 dimension) lexicographically
#pragma unroll
    for (int off = 8; off >= 1; off >>= 1) {
#pragma unroll
        for (int i = 0; i < 32; ++i) {
            float ob = __shfl_xor(best[i], off, 64);
            int   oi = __shfl_xor(bidx[i], off, 64);
            if (ob < best[i] || (ob == best[i] && oi < bidx[i])) { best[i] = ob; bidx[i] = oi; }
        }
    }
    if (l15 == 0) {
#pragma unroll
        for (int s = 0; s < 8; ++s)
#pragma unroll
            for (int r = 0; r < 4; ++r) {
                int pl = s * 16 + l4 * 4 + r;             // wave-local pixel
                red_b[w][pl] = best[s * 4 + r];
                red_i[w][pl] = bidx[s * 4 + r];
            }
    }
    __syncthreads();
    // combine the 4 code-quarter waves (same wr) per pixel, store (best,idx)
    if (tid < 256) {
        int wrg = tid >> 7, pl = tid & 127;
        float bb = red_b[wrg * 4][pl]; int bi = red_i[wrg * 4][pl];
#pragma unroll
        for (int c = 1; c < 4; ++c) {
            float ob = red_b[wrg * 4 + c][pl]; int oi = red_i[wrg * 4 + c][pl];
            if (ob < bb || (ob == bb && oi < bi)) { bb = ob; bi = oi; }
        }
        bestw[nh * NPIX + bM * 256 + tid] = bb;
        bidxw[nh * NPIX + bM * 256 + tid] = bi;
    }
}

// ---------------- K2b: combine the two code-halves into final tokens
__global__ __launch_bounds__(256) void k_argmin2(const float* __restrict__ bestw,
                                                 const int* __restrict__ bidxw,
                                                 float* __restrict__ tok_f) {
    int i = blockIdx.x * 256 + threadIdx.x;   // grid 128
    float b0 = bestw[i], b1 = bestw[NPIX + i];
    int   i0 = bidxw[i], i1 = bidxw[NPIX + i];
    // half-0 indices are always lower -> ties go to i0
    tok_f[i] = (float)((b1 < b0) ? i1 : i0);
}

// ------------------------- K3: gather zq_out = cb[t], recon = postcode[t]
__global__ __launch_bounds__(256) void k_gather(const float* __restrict__ tok_f,
                                                const float* __restrict__ cb,
                                                const float* __restrict__ postcode,
                                                float* __restrict__ zq_out,
                                                float* __restrict__ recon) {
    int b  = blockIdx.x >> 3;                 // grid 1024
    int e0 = (blockIdx.x & 7) * 32;
    int hw = threadIdx.x;
    int t  = (int)tok_f[b * HW + hw];
    const float* cbr = cb       + t * EMB_;
    const float* pcr = postcode + t * CCH;
    float* zq = zq_out + b * (EMB_ * HW) + hw;
    float* rc = recon  + b * (CCH * HW) + hw;
#pragma unroll
    for (int j = 0; j < 32; ++j) {
        int e = e0 + j;
        zq[e * HW] = cbr[e];                  // stores coalesced across hw
        rc[e * HW] = pcr[e];
    }
}

extern "C" void kernel_launch(void* const* d_in, const int* in_sizes, int n_in,
                              void* d_out, int out_size, void* d_ws, size_t ws_size,
                              hipStream_t stream) {
    const float* x      = (const float*)d_in[0];
    const float* cb     = (const float*)d_in[1];
    const float* pre_w  = (const float*)d_in[2];
    const float* pre_b  = (const float*)d_in[3];
    const float* post_w = (const float*)d_in[4];
    const float* post_b = (const float*)d_in[5];

    float* out    = (float*)d_out;
    float* z_out  = out;                       //  8388608 elems
    float* zq_out = out + 8388608;             //  8388608
    float* recon  = out + 16777216;            //  8388608
    float* tok_f  = out + 25165824;            //    32768

    // Scratch-in-output: A3 (33.55 MB) fills zq_out exactly; B3 (4 MB) +
    // best/bidx scratch live in recon. All consumed before k_gather writes.
    _Float16* A3 = (_Float16*)zq_out;          // [2048][64][16][8] fp16
    _Float16* B3 = (_Float16*)recon;           // [256][64][16][8]  fp16
    float* bestw = recon + 1048576;            // 2*32768 floats
    int*   bidxw = (int*)(recon + 1048576 + 2 * NPIX);

    float* csq      = (float*)d_ws;            // 4096 floats
    float* postcode = csq + VOC;               // 4096*256 floats (4 MB)

    k_csq     <<<  16, 256, 0, stream>>>(cb, csq);
    k_postcode<<< 256, 256, 0, stream>>>(cb, post_w, post_b, postcode);
    k_prep_c  <<< 256, 256, 0, stream>>>(cb, B3);
    k_preconv <<<2048, 256, 0, stream>>>(x, pre_w, pre_b, z_out, A3);
    k_dist    <<< 256, 512, 0, stream>>>(z_out, A3, B3, csq, bestw, bidxw);
    k_argmin2 <<< 128, 256, 0, stream>>>(bestw, bidxw, tok_f);
    k_gather  <<<1024, 256, 0, stream>>>(tok_f, cb, postcode, zq_out, recon);
}

// Round 5
// 494.425 us; speedup vs baseline: 1.1585x; 1.0032x over previous
//
#include <hip/hip_runtime.h>
#include <float.h>
#include <stdint.h>

// Problem constants
#define BB   128      // bs*t
#define CCH  256      // z channels
#define EMB_ 256      // embedding dim
#define HW   256      // h*w
#define NPIX 32768    // BB*HW
#define VOC  4096

typedef _Float16 f16x8 __attribute__((ext_vector_type(8)));
typedef float    f32x4 __attribute__((ext_vector_type(4)));

// async global->LDS, 16B per lane, dest = wave-uniform base + lane*16
__device__ __forceinline__ void async16(void* lds, const void* g) {
    __builtin_amdgcn_global_load_lds((const __attribute__((address_space(1))) uint32_t*)g,
                                     (__attribute__((address_space(3))) uint32_t*)lds,
                                     16, 0, 0);
}

// ===================== K_PREP: fused preprocessing =========================
// blocks [0,2048)    : preconv + A3 pack   (identical math to R4 k_preconv)
// blocks [2048,2304) : postcode            (identical math to R4 k_postcode)
// blocks [2304,2560) : prep_c              (identical math to R4 k_prep_c)
// blocks [2560,2576) : csq                 (identical math to R4 k_csq)
// All four are mutually independent; preconv first so its 2048 blocks start
// immediately and the 528 small blocks fill the dispatch tail.
__global__ __launch_bounds__(256) void k_prep(const float* __restrict__ x,
                                              const float* __restrict__ pre_w,
                                              const float* __restrict__ pre_b,
                                              const float* __restrict__ cb,
                                              const float* __restrict__ post_w,
                                              const float* __restrict__ post_b,
                                              float* __restrict__ zout,
                                              _Float16* __restrict__ A3,
                                              _Float16* __restrict__ B3,
                                              float* __restrict__ postcode,
                                              float* __restrict__ csq) {
    __shared__ float smem[8512];              // 34 KB union
    const int bid = blockIdx.x;
    const int tid = threadIdx.x;

    if (bid < 2048) {
        // ---------------- preconv + A3 pack ----------------
        float (*xsT)[260] = (float(*)[260])smem;            // [16][260]
        float (*zsf)[17]  = (float(*)[17])(smem + 4160);    // [256][17]
        int b   = bid >> 4;
        int hw0 = (bid & 15) * 16;
        int cg = tid >> 4, p = tid & 15;
#pragma unroll
        for (int it = 0; it < 16; ++it) {
            int c = it * 16 + cg;
            xsT[p][c] = 2.f * x[b * (CCH * HW) + c * HW + hw0 + p] - 1.f;
        }
        __syncthreads();

        int e = tid;
        float acc[16];
        float bias = pre_b[e];
#pragma unroll
        for (int q = 0; q < 16; ++q) acc[q] = bias;

        const float4* w4p = (const float4*)(pre_w + e * CCH);
        for (int c4 = 0; c4 < 64; ++c4) {
            float4 w4 = w4p[c4];
#pragma unroll
            for (int q = 0; q < 16; ++q) {
                float4 xv = *(const float4*)&xsT[q][c4 * 4];
                acc[q] = fmaf(w4.x, xv.x, fmaf(w4.y, xv.y,
                         fmaf(w4.z, xv.z, fmaf(w4.w, xv.w, acc[q]))));
            }
        }
        float* zo = zout + b * (EMB_ * HW) + e * HW + hw0;
#pragma unroll
        for (int q = 0; q < 4; ++q) {
            float4 s;
            s.x = acc[q * 4 + 0]; s.y = acc[q * 4 + 1];
            s.z = acc[q * 4 + 2]; s.w = acc[q * 4 + 3];
            *(float4*)&zo[q * 4] = s;
        }
        // ---- fused A3 pack (identical math to original k_prep_z) ----
#pragma unroll
        for (int q = 0; q < 16; ++q) zsf[e][q] = acc[q];
        __syncthreads();
        int pixg = b * 16 + (hw0 >> 4);
#pragma unroll
        for (int it = 0; it < 4; ++it) {
            int c = it * 256 + tid;           // 1024 chunks of [row][8 elems]
            int kc8 = c >> 4, row = c & 15;
            int lo = kc8 >> 5;                // 0: hi part, 1: lo part
            int kh = kc8 & 31;
            f16x8 outv;
#pragma unroll
            for (int j = 0; j < 8; ++j) {
                float v = zsf[kh * 8 + j][row] * 256.0f;    // exact 2^8 scale
                _Float16 h = (_Float16)v;                   // RN
                if (lo) h = (_Float16)(v - (float)h);       // exact residual, RN
                outv[j] = h;
            }
            *(f16x8*)(A3 + ((pixg * 64 + kc8) * 128 + row * 8)) = outv;
        }
    } else if (bid < 2304) {
        // ---------------- postcode = post_b + W@cb^T ----------------
        float (*cbs)[EMB_] = (float(*)[EMB_])smem;          // [16][256]
        int v0 = (bid - 2048) * 16;
        int c  = tid;
#pragma unroll
        for (int r = 0; r < 16; ++r)
            cbs[r][c] = cb[(v0 + r) * EMB_ + c];
        __syncthreads();

        float acc[16];
        float bias = post_b[c];
#pragma unroll
        for (int r = 0; r < 16; ++r) acc[r] = bias;

        const float4* w4p = (const float4*)(post_w + c * EMB_);
        for (int e4 = 0; e4 < 64; ++e4) {
            float4 w4 = w4p[e4];
#pragma unroll
            for (int r = 0; r < 16; ++r) {
                float4 c4 = *(const float4*)&cbs[r][e4 * 4];
                acc[r] = fmaf(w4.x, c4.x, fmaf(w4.y, c4.y,
                         fmaf(w4.z, c4.z, fmaf(w4.w, c4.w, acc[r]))));
            }
        }
#pragma unroll
        for (int r = 0; r < 16; ++r)
            postcode[(v0 + r) * CCH + c] = acc[r];
    } else if (bid < 2560) {
        // ---------------- prep_c: codebook fp16 hi/lo pack ----------------
        float (*cs)[17] = (float(*)[17])smem;               // [256][17]
        int vg = bid - 2304;
        int vr = tid >> 4, e0 = (tid & 15) << 4;
        const float* cp = cb + (vg * 16 + vr) * EMB_ + e0;
#pragma unroll
        for (int j = 0; j < 16; ++j)
            cs[e0 + j][vr] = cp[j];
        __syncthreads();
#pragma unroll
        for (int it = 0; it < 4; ++it) {
            int c = it * 256 + tid;
            int kc8 = c >> 4, row = c & 15;
            int lo = kc8 >> 5;
            int kh = kc8 & 31;
            f16x8 outv;
#pragma unroll
            for (int j = 0; j < 8; ++j) {
                float v = cs[kh * 8 + j][row] * 65536.0f;   // exact 2^16 scale
                _Float16 h = (_Float16)v;
                if (lo) h = (_Float16)(v - (float)h);
                outv[j] = h;
            }
            *(f16x8*)(B3 + ((vg * 64 + kc8) * 128 + row * 8)) = outv;
        }
    } else {
        // ---------------- csq ----------------
        int v = (bid - 2560) * 256 + tid;
        const float4* row = (const float4*)(cb + v * EMB_);
        float s = 0.f;
#pragma unroll 8
        for (int q = 0; q < 64; ++q) {
            float4 a = row[q];
            s = fmaf(a.x, a.x, fmaf(a.y, a.y, fmaf(a.z, a.z, fmaf(a.w, a.w, s))));
        }
        csq[v] = s;
    }
}

// --------- K2 staging: BK=32 chunk = 4 contiguous kc8 units at offset kA/kB.
__device__ __forceinline__ void issueA(const _Float16* __restrict__ A3, int bM,
                                       int w, int l, _Float16* dst, int kA) {
#pragma unroll
    for (int i = 0; i < 2; ++i) {
        int pg = 2 * w + i;                           // pixel-group 0..15
        const _Float16* g = A3 + ((bM * 16 + pg) * 64 + kA) * 128 + l * 8;
        async16(dst + pg * 512, g);                   // linear both sides
    }
}

__device__ __forceinline__ void issueB(const _Float16* __restrict__ B3, int vgbase,
                                       int w, int l, _Float16* dst, int kB) {
#pragma unroll
    for (int i = 0; i < 2; ++i) {
        int vg = 2 * w + i;                           // code-group 0..15
        const _Float16* g = B3 + ((vgbase + vg) * 64 + kB) * 128 + l * 8;
        async16(dst + vg * 512, g);
    }
}

// --------------------------------- K2: MFMA distance GEMM + fused argmin
// UNCHANGED from R4 (proven 234 us, tokens bit-identical).
__global__ __launch_bounds__(512) void k_dist(const float* __restrict__ zout,
                                              const _Float16* __restrict__ A3,
                                              const _Float16* __restrict__ B3,
                                              const float* __restrict__ csq,
                                              float* __restrict__ bestw,
                                              int* __restrict__ bidxw) {
    __shared__ __align__(16) _Float16 Ab[3][8192];    // 48 KB (16 KB/chunk)
    __shared__ __align__(16) _Float16 Bb[3][8192];    // 48 KB
    __shared__ float csq_s[2048];                     // 8 KB (this half only)
    __shared__ float zsq_s[256];
    __shared__ float red_b[8][128];
    __shared__ int   red_i[8][128];

    const int tid = threadIdx.x;
    const int l   = tid & 63;
    const int w   = tid >> 6;
    const int l15 = l & 15, l4 = l >> 4;
    const int wr  = w >> 2, wc = w & 3;               // 2M x 4N wave grid
    const int bM  = blockIdx.x & 127;                 // M-tile (256 pixels)
    const int nh  = blockIdx.x >> 7;                  // code half 0/1
    const int vgb = nh * 128;                         // B3 group base

    // prologue: stage chunks 0 and 1
    issueA(A3, bM, w, l, Ab[0], 0);
    issueB(B3, vgb, w, l, Bb[0], 0);
    issueA(A3, bM, w, l, Ab[1], 4);
    issueB(B3, vgb, w, l, Bb[1], 4);

    // csq half -> LDS
#pragma unroll
    for (int j = 0; j < 4; ++j) csq_s[j * 512 + tid] = csq[nh * 2048 + j * 512 + tid];

    // zsq: serial fmaf chain over e (identical rounding to passing kernel)
    if (tid < 256) {
        const float* zp = zout + bM * (EMB_ * HW) + tid;
        float s = 0.f;
        for (int k = 0; k < 256; ++k) { float zv = zp[k * HW]; s = fmaf(zv, zv, s); }
        zsq_s[tid] = s;
    }
    __syncthreads();   // one-time full drain: chunks 0,1 + csq_s + zsq_s ready

    float best[32]; int bidx[32];
#pragma unroll
    for (int i = 0; i < 32; ++i) { best[i] = FLT_MAX; bidx[i] = 0; }

    const f32x4 zero4 = {0.f, 0.f, 0.f, 0.f};
    int cur = 0;
    for (int vt = 0; vt < 8; ++vt) {
        f32x4 acc[8][4];
#pragma unroll
        for (int s = 0; s < 8; ++s)
#pragma unroll
            for (int m = 0; m < 4; ++m) acc[s][m] = zero4;

        for (int kc = 0; kc < 24; ++kc) {
            const int n = vt * 24 + kc;               // global chunk 0..191
            int kc2 = kc + 2, vt2 = vt;
            if (kc2 >= 24) { kc2 -= 24; ++vt2; }
            const int nxt = (cur + 2 >= 3) ? cur - 1 : cur + 2;
            const bool pf = (vt2 < 8);
            const int kA2 = ((kc2 >= 16) ? 32 : 0) + (kc2 & 7) * 4;
            const int kB2 = ((kc2 >= 8 && kc2 < 16) ? 32 : 0) + (kc2 & 7) * 4;

            // ---------------- phase 0: s-half 0 ----------------
            f16x8 af0[4], bf[4];
#pragma unroll
            for (int s = 0; s < 4; ++s)
                af0[s] = *(const f16x8*)&Ab[cur][(wr * 8 + s) * 512 + l4 * 128 + l15 * 8];
#pragma unroll
            for (int m = 0; m < 4; ++m)
                bf[m] = *(const f16x8*)&Bb[cur][(wc * 4 + m) * 512 + l4 * 128 + l15 * 8];
            if (pf) issueA(A3, bM, w, l, Ab[nxt], kA2);
            __builtin_amdgcn_s_barrier();
            asm volatile("s_waitcnt lgkmcnt(0)" ::: "memory");
            __builtin_amdgcn_sched_barrier(0);
            __builtin_amdgcn_s_setprio(1);
#pragma unroll
            for (int s = 0; s < 4; ++s)
#pragma unroll
                for (int m = 0; m < 4; ++m)
                    acc[s][m] = __builtin_amdgcn_mfma_f32_16x16x32_f16(af0[s], bf[m], acc[s][m], 0, 0, 0);
            __builtin_amdgcn_s_setprio(0);
            __builtin_amdgcn_s_barrier();

            // ---------------- phase 1: s-half 1 ----------------
            f16x8 af1[4];
#pragma unroll
            for (int s = 0; s < 4; ++s)
                af1[s] = *(const f16x8*)&Ab[cur][(wr * 8 + 4 + s) * 512 + l4 * 128 + l15 * 8];
            if (pf) issueB(B3, vgb + vt2 * 16, w, l, Bb[nxt], kB2);
            __builtin_amdgcn_s_barrier();
            asm volatile("s_waitcnt lgkmcnt(0)" ::: "memory");
            __builtin_amdgcn_sched_barrier(0);
            __builtin_amdgcn_s_setprio(1);
#pragma unroll
            for (int s = 0; s < 4; ++s)
#pragma unroll
                for (int m = 0; m < 4; ++m)
                    acc[4 + s][m] = __builtin_amdgcn_mfma_f32_16x16x32_f16(af1[s], bf[m], acc[4 + s][m], 0, 0, 0);
            __builtin_amdgcn_s_setprio(0);
            // counted drain: chunk n+1 must be in LDS; chunk n+2 stays in flight
            if (n == 190) { asm volatile("s_waitcnt vmcnt(0)" ::: "memory"); }
            else          { asm volatile("s_waitcnt vmcnt(4)" ::: "memory"); }
            __builtin_amdgcn_s_barrier();
            __builtin_amdgcn_sched_barrier(0);
            cur = (cur + 1 >= 3) ? 0 : cur + 1;
        }

        // ---- fold tile into running argmin (codes ascending per slot)
#pragma unroll
        for (int m = 0; m < 4; ++m) {
            int cl = vt * 256 + (wc * 4 + m) * 16 + l15;   // half-local code
            float cs = csq_s[cl];
            int code = nh * 2048 + cl;
#pragma unroll
            for (int s = 0; s < 8; ++s)
#pragma unroll
                for (int r = 0; r < 4; ++r) {
                    float dd = (zsq_s[wr * 128 + s * 16 + l4 * 4 + r] + cs)
                               - acc[s][m][r] * 0x1p-23f;
                    int pi = s * 4 + r;
                    if (dd < best[pi]) { best[pi] = dd; bidx[pi] = code; }
                }
        }
    }

    // reduce over the 16 code-columns (l15 dimension) lexicographically
#pragma unroll
    for (int off = 8; off >= 1; off >>= 1) {
#pragma unroll
        for (int i = 0; i < 32; ++i) {
            float ob = __shfl_xor(best[i], off, 64);
            int   oi = __shfl_xor(bidx[i], off, 64);
            if (ob < best[i] || (ob == best[i] && oi < bidx[i])) { best[i] = ob; bidx[i] = oi; }
        }
    }
    if (l15 == 0) {
#pragma unroll
        for (int s = 0; s < 8; ++s)
#pragma unroll
            for (int r = 0; r < 4; ++r) {
                int pl = s * 16 + l4 * 4 + r;             // wave-local pixel
                red_b[w][pl] = best[s * 4 + r];
                red_i[w][pl] = bidx[s * 4 + r];
            }
    }
    __syncthreads();
    // combine the 4 code-quarter waves (same wr) per pixel, store (best,idx)
    if (tid < 256) {
        int wrg = tid >> 7, pl = tid & 127;
        float bb = red_b[wrg * 4][pl]; int bi = red_i[wrg * 4][pl];
#pragma unroll
        for (int c = 1; c < 4; ++c) {
            float ob = red_b[wrg * 4 + c][pl]; int oi = red_i[wrg * 4 + c][pl];
            if (ob < bb || (ob == bb && oi < bi)) { bb = ob; bi = oi; }
        }
        bestw[nh * NPIX + bM * 256 + tid] = bb;
        bidxw[nh * NPIX + bM * 256 + tid] = bi;
    }
}

// ---------------- K2b: combine the two code-halves into final tokens
// (fallback path when bestw/bidxw must live in the recon output region)
__global__ __launch_bounds__(256) void k_argmin2(const float* __restrict__ bestw,
                                                 const int* __restrict__ bidxw,
                                                 float* __restrict__ tok_f) {
    int i = blockIdx.x * 256 + threadIdx.x;   // grid 128
    float b0 = bestw[i], b1 = bestw[NPIX + i];
    int   i0 = bidxw[i], i1 = bidxw[NPIX + i];
    // half-0 indices are always lower -> ties go to i0
    tok_f[i] = (float)((b1 < b0) ? i1 : i0);
}

// ------------------------- K3: gather zq_out = cb[t], recon = postcode[t]
__global__ __launch_bounds__(256) void k_gather(const float* __restrict__ tok_f,
                                                const float* __restrict__ cb,
                                                const float* __restrict__ postcode,
                                                float* __restrict__ zq_out,
                                                float* __restrict__ recon) {
    int b  = blockIdx.x >> 3;                 // grid 1024
    int e0 = (blockIdx.x & 7) * 32;
    int hw = threadIdx.x;
    int t  = (int)tok_f[b * HW + hw];
    const float* cbr = cb       + t * EMB_;
    const float* pcr = postcode + t * CCH;
    float* zq = zq_out + b * (EMB_ * HW) + hw;
    float* rc = recon  + b * (CCH * HW) + hw;
#pragma unroll
    for (int j = 0; j < 32; ++j) {
        int e = e0 + j;
        zq[e * HW] = cbr[e];                  // stores coalesced across hw
        rc[e * HW] = pcr[e];
    }
}

// ---- K3f: gather with inline half-combine (bestw/bidxw in workspace,
//           so no write-after-read hazard with recon). e0==0 writes tok_f.
__global__ __launch_bounds__(256) void k_gather_fused(const float* __restrict__ bestw,
                                                      const int* __restrict__ bidxw,
                                                      const float* __restrict__ cb,
                                                      const float* __restrict__ postcode,
                                                      float* __restrict__ zq_out,
                                                      float* __restrict__ recon,
                                                      float* __restrict__ tok_f) {
    int b  = blockIdx.x >> 3;                 // grid 1024
    int e0 = (blockIdx.x & 7) * 32;
    int hw = threadIdx.x;
    int i  = b * HW + hw;
    float b0 = bestw[i], b1 = bestw[NPIX + i];
    int   i0 = bidxw[i], i1 = bidxw[NPIX + i];
    int   t  = (b1 < b0) ? i1 : i0;           // identical to k_argmin2
    if (e0 == 0) tok_f[i] = (float)t;
    const float* cbr = cb       + t * EMB_;
    const float* pcr = postcode + t * CCH;
    float* zq = zq_out + b * (EMB_ * HW) + hw;
    float* rc = recon  + b * (CCH * HW) + hw;
#pragma unroll
    for (int j = 0; j < 32; ++j) {
        int e = e0 + j;
        zq[e * HW] = cbr[e];
        rc[e * HW] = pcr[e];
    }
}

extern "C" void kernel_launch(void* const* d_in, const int* in_sizes, int n_in,
                              void* d_out, int out_size, void* d_ws, size_t ws_size,
                              hipStream_t stream) {
    const float* x      = (const float*)d_in[0];
    const float* cb     = (const float*)d_in[1];
    const float* pre_w  = (const float*)d_in[2];
    const float* pre_b  = (const float*)d_in[3];
    const float* post_w = (const float*)d_in[4];
    const float* post_b = (const float*)d_in[5];

    float* out    = (float*)d_out;
    float* z_out  = out;                       //  8388608 elems
    float* zq_out = out + 8388608;             //  8388608
    float* recon  = out + 16777216;            //  8388608
    float* tok_f  = out + 25165824;            //    32768

    // Scratch-in-output: A3 (33.55 MB) fills zq_out exactly; B3 (4.19 MB)
    // lives at the head of recon. Both consumed before gather writes.
    _Float16* A3 = (_Float16*)zq_out;          // [2048][64][16][8] fp16
    _Float16* B3 = (_Float16*)recon;           // [256][64][16][8]  fp16

    float* csq      = (float*)d_ws;            // 4096 floats
    float* postcode = csq + VOC;               // 4096*256 floats (4 MB)

    // bestw/bidxw: prefer workspace (enables fused gather, no WAR hazard);
    // fall back to recon tail + separate argmin2 (R4's proven layout).
    size_t need = (size_t)(VOC + VOC * CCH + 4 * NPIX) * sizeof(float);
    bool fused = (ws_size >= need);
    float* bestw; int* bidxw;
    if (fused) {
        bestw = postcode + (size_t)VOC * CCH;  // 2*NPIX floats
        bidxw = (int*)(bestw + 2 * NPIX);      // 2*NPIX ints
    } else {
        bestw = recon + 1048576;
        bidxw = (int*)(recon + 1048576 + 2 * NPIX);
    }

    k_prep<<<2576, 256, 0, stream>>>(x, pre_w, pre_b, cb, post_w, post_b,
                                     z_out, A3, B3, postcode, csq);
    k_dist<<< 256, 512, 0, stream>>>(z_out, A3, B3, csq, bestw, bidxw);
    if (fused) {
        k_gather_fused<<<1024, 256, 0, stream>>>(bestw, bidxw, cb, postcode,
                                                 zq_out, recon, tok_f);
    } else {
        k_argmin2<<< 128, 256, 0, stream>>>(bestw, bidxw, tok_f);
        k_gather <<<1024, 256, 0, stream>>>(tok_f, cb, postcode, zq_out, recon);
    }
}

// Round 6
// 391.342 us; speedup vs baseline: 1.4637x; 1.2634x over previous
//
#include <hip/hip_runtime.h>
#include <float.h>
#include <stdint.h>

// Problem constants
#define BB   128      // bs*t
#define CCH  256      // z channels
#define EMB_ 256      // embedding dim
#define HW   256      // h*w
#define NPIX 32768    // BB*HW
#define VOC  4096

typedef _Float16 f16x8 __attribute__((ext_vector_type(8)));
typedef float    f32x4 __attribute__((ext_vector_type(4)));

// async global->LDS, 16B per lane, dest = wave-uniform base + lane*16
__device__ __forceinline__ void async16(void* lds, const void* g) {
    __builtin_amdgcn_global_load_lds((const __attribute__((address_space(1))) uint32_t*)g,
                                     (__attribute__((address_space(3))) uint32_t*)lds,
                                     16, 0, 0);
}

// ===================== K_PREP: small preprocessing (544 blocks) ============
// [0,256)   postcode = post_b + post_w@cb^T   (identical math to R5)
// [256,512) prep_c: codebook fp16 hi/lo pack  (identical math to R5)
// [512,528) csq                                (identical math to R5)
// [528,544) prep_w: pre_w scaled split -> W3[eg16][u64][row16][e8]
//           hi: u=c8 (0..31): fl16(w*16); lo: u=32+c8: fl16((w*16-hi)*4096)
__global__ __launch_bounds__(256) void k_prep(const float* __restrict__ cb,
                                              const float* __restrict__ post_w,
                                              const float* __restrict__ post_b,
                                              const float* __restrict__ pre_w,
                                              float* __restrict__ postcode,
                                              _Float16* __restrict__ B3,
                                              float* __restrict__ csq,
                                              _Float16* __restrict__ W3) {
    __shared__ float smem[4352];              // 17 KB union
    const int bid = blockIdx.x;
    const int tid = threadIdx.x;

    if (bid < 256) {
        // ---------------- postcode ----------------
        float (*cbs)[EMB_] = (float(*)[EMB_])smem;          // [16][256]
        int v0 = bid * 16;
        int c  = tid;
#pragma unroll
        for (int r = 0; r < 16; ++r)
            cbs[r][c] = cb[(v0 + r) * EMB_ + c];
        __syncthreads();
        float acc[16];
        float bias = post_b[c];
#pragma unroll
        for (int r = 0; r < 16; ++r) acc[r] = bias;
        const float4* w4p = (const float4*)(post_w + c * EMB_);
        for (int e4 = 0; e4 < 64; ++e4) {
            float4 w4 = w4p[e4];
#pragma unroll
            for (int r = 0; r < 16; ++r) {
                float4 c4 = *(const float4*)&cbs[r][e4 * 4];
                acc[r] = fmaf(w4.x, c4.x, fmaf(w4.y, c4.y,
                         fmaf(w4.z, c4.z, fmaf(w4.w, c4.w, acc[r]))));
            }
        }
#pragma unroll
        for (int r = 0; r < 16; ++r)
            postcode[(v0 + r) * CCH + c] = acc[r];
    } else if (bid < 512) {
        // ---------------- prep_c ----------------
        float (*cs)[17] = (float(*)[17])smem;               // [256][17]
        int vg = bid - 256;
        int vr = tid >> 4, e0 = (tid & 15) << 4;
        const float* cp = cb + (vg * 16 + vr) * EMB_ + e0;
#pragma unroll
        for (int j = 0; j < 16; ++j)
            cs[e0 + j][vr] = cp[j];
        __syncthreads();
#pragma unroll
        for (int it = 0; it < 4; ++it) {
            int c = it * 256 + tid;
            int kc8 = c >> 4, row = c & 15;
            int lo = kc8 >> 5;
            int kh = kc8 & 31;
            f16x8 outv;
#pragma unroll
            for (int j = 0; j < 8; ++j) {
                float v = cs[kh * 8 + j][row] * 65536.0f;   // exact 2^16 scale
                _Float16 h = (_Float16)v;
                if (lo) h = (_Float16)(v - (float)h);
                outv[j] = h;
            }
            *(f16x8*)(B3 + ((vg * 64 + kc8) * 128 + row * 8)) = outv;
        }
    } else if (bid < 528) {
        // ---------------- csq ----------------
        int v = (bid - 512) * 256 + tid;
        const float4* row = (const float4*)(cb + v * EMB_);
        float s = 0.f;
#pragma unroll 8
        for (int q = 0; q < 64; ++q) {
            float4 a = row[q];
            s = fmaf(a.x, a.x, fmaf(a.y, a.y, fmaf(a.z, a.z, fmaf(a.w, a.w, s))));
        }
        csq[v] = s;
    } else {
        // ---------------- prep_w: scaled split of pre_w ----------------
        int eg = bid - 528;                   // 0..15
#pragma unroll
        for (int i = 0; i < 4; ++i) {
            int flat = i * 256 + tid;         // 0..1023 = [u64][row16]
            int u = flat >> 4, row = flat & 15;
            int part = u >> 5, c8 = u & 31;
            const float* wp = pre_w + (eg * 16 + row) * CCH + c8 * 8;
            f16x8 outv;
#pragma unroll
            for (int j = 0; j < 8; ++j) {
                float v = wp[j] * 16.0f;                    // exact 2^4 scale
                _Float16 h = (_Float16)v;
                if (part) h = (_Float16)((v - (float)h) * 4096.0f); // exact*2^12, RN
                outv[j] = h;
            }
            *(f16x8*)(W3 + ((eg * 64 + u) * 128 + row * 8)) = outv;
        }
    }
}

// ============ K1: z-GEMM on MFMA (replaces fp32-VALU preconv) ==============
// z*16 = wh.xh + 2^-12 (wh.xl + wl.xh)  [wl.xl ~2^-24 dropped, dz~1e-9]
// z = fmaf(accB, 2^-12, accA)*2^-4 + pre_b. Then z_out store + A3 pack
// (pack math byte-identical to R5: v=z*256; hi=fl16(v); lo=fl16(v-hi)).
// Grid 256 (bM: 128-pixel n-tile), 512 thr, 8 waves 2M(n? no: rows=e)...
// waves: 2 n-rows (wr) x 4 e-cols (wc); wave tile 64e x 64n; acc 2x[4][4].
__global__ __launch_bounds__(512) void k_zgemm(const float* __restrict__ x,
                                               const _Float16* __restrict__ W3,
                                               const float* __restrict__ pre_b,
                                               float* __restrict__ zout,
                                               _Float16* __restrict__ A3) {
    __shared__ __align__(16) char smem[99328];
    // offsets: Wh[2]@0/16384, Wl[2]@32768/49152 (16KB each)
    //          Xh[2]@65536/73728, Xl[2]@81920/90112 (8KB each)
    //          pbs@98304 (1KB). Epilogue zbuf aliases @0 (8 waves x 5120B).
    float* pbs = (float*)(smem + 98304);

    const int tid = threadIdx.x;
    const int l   = tid & 63;
    const int w   = tid >> 6;
    const int l15 = l & 15, l4 = l >> 4;
    const int wr  = w >> 2, wc = w & 3;
    const int bM  = blockIdx.x;
    const int b   = bM >> 1, hw0 = (bM & 1) * 128;

    const int xng = tid >> 6, xu = (tid >> 4) & 3, xrow = tid & 15;
    const float* xbase = x + (size_t)b * (CCH * HW) + hw0 + xng * 16 + xrow;

#define STAGE_W(CC, BUF) {                                                   \
    _Pragma("unroll")                                                        \
    for (int i = 0; i < 2; ++i) {                                            \
        int flat = i * 512 + tid; int eg = flat >> 6, sub = flat & 63;       \
        async16((_Float16*)(smem + (BUF) * 16384) + flat * 8,                \
                W3 + (eg * 64 + (CC) * 4) * 128 + sub * 8);                  \
        async16((_Float16*)(smem + 32768 + (BUF) * 16384) + flat * 8,        \
                W3 + (eg * 64 + 32 + (CC) * 4) * 128 + sub * 8);             \
    } }

#define STAGE_X(CC, BUF) {                                                   \
    const float* xp_ = xbase + ((CC) * 32 + xu * 8) * HW;                    \
    f16x8 hv, lv;                                                            \
    _Pragma("unroll")                                                        \
    for (int j = 0; j < 8; ++j) {                                            \
        float xv = 2.0f * xp_[j * HW] - 1.0f;        /* exact */             \
        _Float16 h = (_Float16)xv;                                           \
        lv[j] = (_Float16)((xv - (float)h) * 4096.0f); /* exact*2^12, RN */  \
        hv[j] = h;                                                           \
    }                                                                        \
    *(f16x8*)((_Float16*)(smem + 65536 + (BUF) * 8192) + tid * 8) = hv;      \
    *(f16x8*)((_Float16*)(smem + 81920 + (BUF) * 8192) + tid * 8) = lv;      \
    }

    if (tid < 256) pbs[tid] = pre_b[tid];
    STAGE_W(0, 0)
    STAGE_X(0, 0)
    __syncthreads();

    f32x4 accA[4][4], accB[4][4];
    const f32x4 zero4 = {0.f, 0.f, 0.f, 0.f};
#pragma unroll
    for (int m = 0; m < 4; ++m)
#pragma unroll
        for (int s = 0; s < 4; ++s) { accA[m][s] = zero4; accB[m][s] = zero4; }

    int buf = 0;
    for (int cc = 0; cc < 8; ++cc) {
        if (cc < 7) { STAGE_W(cc + 1, buf ^ 1) STAGE_X(cc + 1, buf ^ 1) }
        const _Float16* WhC = (const _Float16*)(smem + buf * 16384);
        const _Float16* WlC = (const _Float16*)(smem + 32768 + buf * 16384);
        const _Float16* XhC = (const _Float16*)(smem + 65536 + buf * 8192);
        const _Float16* XlC = (const _Float16*)(smem + 81920 + buf * 8192);
        f16x8 whf[4], wlf[4], xhf[4], xlf[4];
#pragma unroll
        for (int m = 0; m < 4; ++m) {
            whf[m] = *(const f16x8*)&WhC[((wc * 4 + m) * 64 + l4 * 16 + l15) * 8];
            wlf[m] = *(const f16x8*)&WlC[((wc * 4 + m) * 64 + l4 * 16 + l15) * 8];
        }
#pragma unroll
        for (int s = 0; s < 4; ++s) {
            xhf[s] = *(const f16x8*)&XhC[((wr * 4 + s) * 64 + l4 * 16 + l15) * 8];
            xlf[s] = *(const f16x8*)&XlC[((wr * 4 + s) * 64 + l4 * 16 + l15) * 8];
        }
#pragma unroll
        for (int m = 0; m < 4; ++m)
#pragma unroll
            for (int s = 0; s < 4; ++s)
                accA[m][s] = __builtin_amdgcn_mfma_f32_16x16x32_f16(whf[m], xhf[s], accA[m][s], 0, 0, 0);
#pragma unroll
        for (int m = 0; m < 4; ++m)
#pragma unroll
            for (int s = 0; s < 4; ++s)
                accB[m][s] = __builtin_amdgcn_mfma_f32_16x16x32_f16(whf[m], xlf[s], accB[m][s], 0, 0, 0);
#pragma unroll
        for (int m = 0; m < 4; ++m)
#pragma unroll
            for (int s = 0; s < 4; ++s)
                accB[m][s] = __builtin_amdgcn_mfma_f32_16x16x32_f16(wlf[m], xhf[s], accB[m][s], 0, 0, 0);
        __syncthreads();
        buf ^= 1;
    }

    // ---- epilogue: z = combine + bias; store z_out; pack A3 (per-wave LDS)
    float* zw = (float*)(smem + w * 5120);    // [64 n][20 floats] this wave
    const size_t zbase = (size_t)b * (EMB_ * HW) + hw0;
#pragma unroll
    for (int m = 0; m < 4; ++m) {
        asm volatile("s_waitcnt lgkmcnt(0)" ::: "memory");   // prev pack reads done
        __builtin_amdgcn_sched_barrier(0);
        f32x4 zv[4];
#pragma unroll
        for (int s = 0; s < 4; ++s) {
#pragma unroll
            for (int r = 0; r < 4; ++r) {
                float g = fmaf(accB[m][s][r], 0x1p-12f, accA[m][s][r]) * 0x1p-4f;
                zv[s][r] = g + pbs[wc * 64 + m * 16 + l4 * 4 + r];
            }
            *(f32x4*)(zw + (s * 16 + l15) * 20 + l4 * 4) = zv[s];
#pragma unroll
            for (int r = 0; r < 4; ++r)
                zout[zbase + (size_t)(wc * 64 + m * 16 + l4 * 4 + r) * HW
                     + wr * 64 + s * 16 + l15] = zv[s][r];
        }
        asm volatile("s_waitcnt lgkmcnt(0)" ::: "memory");   // zbuf writes visible
        __builtin_amdgcn_sched_barrier(0);
#pragma unroll
        for (int o = 0; o < 4; ++o) {
            int flat = o * 64 + l;
            int part = flat >> 7, rest = flat & 127;
            int pg = rest >> 5, uq = (rest >> 4) & 1, row = rest & 15;
            int nloc = pg * 16 + row;
            float4 va = *(const float4*)(zw + nloc * 20 + uq * 8);
            float4 vb = *(const float4*)(zw + nloc * 20 + uq * 8 + 4);
            float vs[8] = {va.x, va.y, va.z, va.w, vb.x, vb.y, vb.z, vb.w};
            f16x8 outv;
#pragma unroll
            for (int j = 0; j < 8; ++j) {
                float v = vs[j] * 256.0f;                    // exact 2^8 scale
                _Float16 h = (_Float16)v;
                if (part) h = (_Float16)(v - (float)h);      // exact residual, RN
                outv[j] = h;
            }
            *(f16x8*)(A3 + ((size_t)(bM * 8 + wr * 4 + pg) * 64
                            + part * 32 + wc * 8 + m * 2 + uq) * 128 + row * 8) = outv;
        }
    }
#undef STAGE_W
#undef STAGE_X
}

// --------- K2 staging: BK=32 chunk = 4 contiguous kc8 units at offset kA/kB.
__device__ __forceinline__ void issueA(const _Float16* __restrict__ A3, int bM,
                                       int w, int l, _Float16* dst, int kA) {
#pragma unroll
    for (int i = 0; i < 2; ++i) {
        int pg = 2 * w + i;                           // pixel-group 0..15
        const _Float16* g = A3 + ((bM * 16 + pg) * 64 + kA) * 128 + l * 8;
        async16(dst + pg * 512, g);                   // linear both sides
    }
}

__device__ __forceinline__ void issueB(const _Float16* __restrict__ B3, int vgbase,
                                       int w, int l, _Float16* dst, int kB) {
#pragma unroll
    for (int i = 0; i < 2; ++i) {
        int vg = 2 * w + i;                           // code-group 0..15
        const _Float16* g = B3 + ((vgbase + vg) * 64 + kB) * 128 + l * 8;
        async16(dst + vg * 512, g);
    }
}

// --------------------------------- K2: MFMA distance GEMM + fused argmin
// UNCHANGED from R4/R5 (proven 234 us, tokens verified).
__global__ __launch_bounds__(512) void k_dist(const float* __restrict__ zout,
                                              const _Float16* __restrict__ A3,
                                              const _Float16* __restrict__ B3,
                                              const float* __restrict__ csq,
                                              float* __restrict__ bestw,
                                              int* __restrict__ bidxw) {
    __shared__ __align__(16) _Float16 Ab[3][8192];    // 48 KB (16 KB/chunk)
    __shared__ __align__(16) _Float16 Bb[3][8192];    // 48 KB
    __shared__ float csq_s[2048];                     // 8 KB (this half only)
    __shared__ float zsq_s[256];
    __shared__ float red_b[8][128];
    __shared__ int   red_i[8][128];

    const int tid = threadIdx.x;
    const int l   = tid & 63;
    const int w   = tid >> 6;
    const int l15 = l & 15, l4 = l >> 4;
    const int wr  = w >> 2, wc = w & 3;               // 2M x 4N wave grid
    const int bM  = blockIdx.x & 127;                 // M-tile (256 pixels)
    const int nh  = blockIdx.x >> 7;                  // code half 0/1
    const int vgb = nh * 128;                         // B3 group base

    // prologue: stage chunks 0 and 1
    issueA(A3, bM, w, l, Ab[0], 0);
    issueB(B3, vgb, w, l, Bb[0], 0);
    issueA(A3, bM, w, l, Ab[1], 4);
    issueB(B3, vgb, w, l, Bb[1], 4);

    // csq half -> LDS
#pragma unroll
    for (int j = 0; j < 4; ++j) csq_s[j * 512 + tid] = csq[nh * 2048 + j * 512 + tid];

    // zsq: serial fmaf chain over e (identical rounding to passing kernel)
    if (tid < 256) {
        const float* zp = zout + bM * (EMB_ * HW) + tid;
        float s = 0.f;
        for (int k = 0; k < 256; ++k) { float zv = zp[k * HW]; s = fmaf(zv, zv, s); }
        zsq_s[tid] = s;
    }
    __syncthreads();   // one-time full drain: chunks 0,1 + csq_s + zsq_s ready

    float best[32]; int bidx[32];
#pragma unroll
    for (int i = 0; i < 32; ++i) { best[i] = FLT_MAX; bidx[i] = 0; }

    const f32x4 zero4 = {0.f, 0.f, 0.f, 0.f};
    int cur = 0;
    for (int vt = 0; vt < 8; ++vt) {
        f32x4 acc[8][4];
#pragma unroll
        for (int s = 0; s < 8; ++s)
#pragma unroll
            for (int m = 0; m < 4; ++m) acc[s][m] = zero4;

        for (int kc = 0; kc < 24; ++kc) {
            const int n = vt * 24 + kc;               // global chunk 0..191
            int kc2 = kc + 2, vt2 = vt;
            if (kc2 >= 24) { kc2 -= 24; ++vt2; }
            const int nxt = (cur + 2 >= 3) ? cur - 1 : cur + 2;
            const bool pf = (vt2 < 8);
            const int kA2 = ((kc2 >= 16) ? 32 : 0) + (kc2 & 7) * 4;
            const int kB2 = ((kc2 >= 8 && kc2 < 16) ? 32 : 0) + (kc2 & 7) * 4;

            // ---------------- phase 0: s-half 0 ----------------
            f16x8 af0[4], bf[4];
#pragma unroll
            for (int s = 0; s < 4; ++s)
                af0[s] = *(const f16x8*)&Ab[cur][(wr * 8 + s) * 512 + l4 * 128 + l15 * 8];
#pragma unroll
            for (int m = 0; m < 4; ++m)
                bf[m] = *(const f16x8*)&Bb[cur][(wc * 4 + m) * 512 + l4 * 128 + l15 * 8];
            if (pf) issueA(A3, bM, w, l, Ab[nxt], kA2);
            __builtin_amdgcn_s_barrier();
            asm volatile("s_waitcnt lgkmcnt(0)" ::: "memory");
            __builtin_amdgcn_sched_barrier(0);
            __builtin_amdgcn_s_setprio(1);
#pragma unroll
            for (int s = 0; s < 4; ++s)
#pragma unroll
                for (int m = 0; m < 4; ++m)
                    acc[s][m] = __builtin_amdgcn_mfma_f32_16x16x32_f16(af0[s], bf[m], acc[s][m], 0, 0, 0);
            __builtin_amdgcn_s_setprio(0);
            __builtin_amdgcn_s_barrier();

            // ---------------- phase 1: s-half 1 ----------------
            f16x8 af1[4];
#pragma unroll
            for (int s = 0; s < 4; ++s)
                af1[s] = *(const f16x8*)&Ab[cur][(wr * 8 + 4 + s) * 512 + l4 * 128 + l15 * 8];
            if (pf) issueB(B3, vgb + vt2 * 16, w, l, Bb[nxt], kB2);
            __builtin_amdgcn_s_barrier();
            asm volatile("s_waitcnt lgkmcnt(0)" ::: "memory");
            __builtin_amdgcn_sched_barrier(0);
            __builtin_amdgcn_s_setprio(1);
#pragma unroll
            for (int s = 0; s < 4; ++s)
#pragma unroll
                for (int m = 0; m < 4; ++m)
                    acc[4 + s][m] = __builtin_amdgcn_mfma_f32_16x16x32_f16(af1[s], bf[m], acc[4 + s][m], 0, 0, 0);
            __builtin_amdgcn_s_setprio(0);
            // counted drain: chunk n+1 must be in LDS; chunk n+2 stays in flight
            if (n == 190) { asm volatile("s_waitcnt vmcnt(0)" ::: "memory"); }
            else          { asm volatile("s_waitcnt vmcnt(4)" ::: "memory"); }
            __builtin_amdgcn_s_barrier();
            __builtin_amdgcn_sched_barrier(0);
            cur = (cur + 1 >= 3) ? 0 : cur + 1;
        }

        // ---- fold tile into running argmin (codes ascending per slot)
#pragma unroll
        for (int m = 0; m < 4; ++m) {
            int cl = vt * 256 + (wc * 4 + m) * 16 + l15;   // half-local code
            float cs = csq_s[cl];
            int code = nh * 2048 + cl;
#pragma unroll
            for (int s = 0; s < 8; ++s)
#pragma unroll
                for (int r = 0; r < 4; ++r) {
                    float dd = (zsq_s[wr * 128 + s * 16 + l4 * 4 + r] + cs)
                               - acc[s][m][r] * 0x1p-23f;
                    int pi = s * 4 + r;
                    if (dd < best[pi]) { best[pi] = dd; bidx[pi] = code; }
                }
        }
    }

    // reduce over the 16 code-columns (l15 dimension) lexicographically
#pragma unroll
    for (int off = 8; off >= 1; off >>= 1) {
#pragma unroll
        for (int i = 0; i < 32; ++i) {
            float ob = __shfl_xor(best[i], off, 64);
            int   oi = __shfl_xor(bidx[i], off, 64);
            if (ob < best[i] || (ob == best[i] && oi < bidx[i])) { best[i] = ob; bidx[i] = oi; }
        }
    }
    if (l15 == 0) {
#pragma unroll
        for (int s = 0; s < 8; ++s)
#pragma unroll
            for (int r = 0; r < 4; ++r) {
                int pl = s * 16 + l4 * 4 + r;             // wave-local pixel
                red_b[w][pl] = best[s * 4 + r];
                red_i[w][pl] = bidx[s * 4 + r];
            }
    }
    __syncthreads();
    // combine the 4 code-quarter waves (same wr) per pixel, store (best,idx)
    if (tid < 256) {
        int wrg = tid >> 7, pl = tid & 127;
        float bb = red_b[wrg * 4][pl]; int bi = red_i[wrg * 4][pl];
#pragma unroll
        for (int c = 1; c < 4; ++c) {
            float ob = red_b[wrg * 4 + c][pl]; int oi = red_i[wrg * 4 + c][pl];
            if (ob < bb || (ob == bb && oi < bi)) { bb = ob; bi = oi; }
        }
        bestw[nh * NPIX + bM * 256 + tid] = bb;
        bidxw[nh * NPIX + bM * 256 + tid] = bi;
    }
}

// ---------------- K2b: combine the two code-halves into final tokens
__global__ __launch_bounds__(256) void k_argmin2(const float* __restrict__ bestw,
                                                 const int* __restrict__ bidxw,
                                                 float* __restrict__ tok_f) {
    int i = blockIdx.x * 256 + threadIdx.x;   // grid 128
    float b0 = bestw[i], b1 = bestw[NPIX + i];
    int   i0 = bidxw[i], i1 = bidxw[NPIX + i];
    tok_f[i] = (float)((b1 < b0) ? i1 : i0);  // half-0 wins ties (lower idx)
}

// ------------------------- K3: gather zq_out = cb[t], recon = postcode[t]
__global__ __launch_bounds__(256) void k_gather(const float* __restrict__ tok_f,
                                                const float* __restrict__ cb,
                                                const float* __restrict__ postcode,
                                                float* __restrict__ zq_out,
                                                float* __restrict__ recon) {
    int b  = blockIdx.x >> 3;                 // grid 1024
    int e0 = (blockIdx.x & 7) * 32;
    int hw = threadIdx.x;
    int t  = (int)tok_f[b * HW + hw];
    const float* cbr = cb       + t * EMB_;
    const float* pcr = postcode + t * CCH;
    float* zq = zq_out + b * (EMB_ * HW) + hw;
    float* rc = recon  + b * (CCH * HW) + hw;
#pragma unroll
    for (int j = 0; j < 32; ++j) {
        int e = e0 + j;
        zq[e * HW] = cbr[e];
        rc[e * HW] = pcr[e];
    }
}

// ---- K3f: gather with inline half-combine (bestw/bidxw in workspace)
__global__ __launch_bounds__(256) void k_gather_fused(const float* __restrict__ bestw,
                                                      const int* __restrict__ bidxw,
                                                      const float* __restrict__ cb,
                                                      const float* __restrict__ postcode,
                                                      float* __restrict__ zq_out,
                                                      float* __restrict__ recon,
                                                      float* __restrict__ tok_f) {
    int b  = blockIdx.x >> 3;                 // grid 1024
    int e0 = (blockIdx.x & 7) * 32;
    int hw = threadIdx.x;
    int i  = b * HW + hw;
    float b0 = bestw[i], b1 = bestw[NPIX + i];
    int   i0 = bidxw[i], i1 = bidxw[NPIX + i];
    int   t  = (b1 < b0) ? i1 : i0;
    if (e0 == 0) tok_f[i] = (float)t;
    const float* cbr = cb       + t * EMB_;
    const float* pcr = postcode + t * CCH;
    float* zq = zq_out + b * (EMB_ * HW) + hw;
    float* rc = recon  + b * (CCH * HW) + hw;
#pragma unroll
    for (int j = 0; j < 32; ++j) {
        int e = e0 + j;
        zq[e * HW] = cbr[e];
        rc[e * HW] = pcr[e];
    }
}

extern "C" void kernel_launch(void* const* d_in, const int* in_sizes, int n_in,
                              void* d_out, int out_size, void* d_ws, size_t ws_size,
                              hipStream_t stream) {
    const float* x      = (const float*)d_in[0];
    const float* cb     = (const float*)d_in[1];
    const float* pre_w  = (const float*)d_in[2];
    const float* pre_b  = (const float*)d_in[3];
    const float* post_w = (const float*)d_in[4];
    const float* post_b = (const float*)d_in[5];

    float* out    = (float*)d_out;
    float* z_out  = out;                       //  8388608 elems
    float* zq_out = out + 8388608;             //  8388608
    float* recon  = out + 16777216;            //  8388608
    float* tok_f  = out + 25165824;            //    32768

    // Scratch-in-output: A3 (33.55 MB) fills zq_out exactly; B3 (4 MB) at
    // recon head; fallback bestw/bidxw + W3 in recon tail. All consumed
    // before gather writes recon.
    _Float16* A3 = (_Float16*)zq_out;          // [2048][64][16][8] fp16
    _Float16* B3 = (_Float16*)recon;           // [256][64][16][8]  fp16
    _Float16* W3 = (_Float16*)(recon + 1048576 + 4 * NPIX);  // 131072 f16

    float* csq      = (float*)d_ws;            // 4096 floats
    float* postcode = csq + VOC;               // 4096*256 floats (4 MB)

    size_t need = (size_t)(VOC + VOC * CCH + 4 * NPIX) * sizeof(float);
    bool fused = (ws_size >= need);
    float* bestw; int* bidxw;
    if (fused) {
        bestw = postcode + (size_t)VOC * CCH;  // 2*NPIX floats
        bidxw = (int*)(bestw + 2 * NPIX);      // 2*NPIX ints
    } else {
        bestw = recon + 1048576;
        bidxw = (int*)(recon + 1048576 + 2 * NPIX);
    }

    k_prep <<< 544, 256, 0, stream>>>(cb, post_w, post_b, pre_w,
                                      postcode, B3, csq, W3);
    k_zgemm<<< 256, 512, 0, stream>>>(x, W3, pre_b, z_out, A3);
    k_dist <<< 256, 512, 0, stream>>>(z_out, A3, B3, csq, bestw, bidxw);
    if (fused) {
        k_gather_fused<<<1024, 256, 0, stream>>>(bestw, bidxw, cb, postcode,
                                                 zq_out, recon, tok_f);
    } else {
        k_argmin2<<< 128, 256, 0, stream>>>(bestw, bidxw, tok_f);
        k_gather <<<1024, 256, 0, stream>>>(tok_f, cb, postcode, zq_out, recon);
    }
}

// Round 7
// 390.579 us; speedup vs baseline: 1.4665x; 1.0020x over previous
//
#include <hip/hip_runtime.h>
#include <float.h>
#include <stdint.h>

// Problem constants
#define BB   128      // bs*t
#define CCH  256      // z channels
#define EMB_ 256      // embedding dim
#define HW   256      // h*w
#define NPIX 32768    // BB*HW
#define VOC  4096

typedef _Float16 f16x8 __attribute__((ext_vector_type(8)));
typedef float    f32x4 __attribute__((ext_vector_type(4)));

// async global->LDS, 16B per lane, dest = wave-uniform base + lane*16
__device__ __forceinline__ void async16(void* lds, const void* g) {
    __builtin_amdgcn_global_load_lds((const __attribute__((address_space(1))) uint32_t*)g,
                                     (__attribute__((address_space(3))) uint32_t*)lds,
                                     16, 0, 0);
}

// ===================== K_PREP: small preprocessing (544 blocks) ============
// [0,256)   postcode = post_b + post_w@cb^T
// [256,512) prep_c: codebook fp16 hi/lo pack
// [512,528) csq
// [528,544) prep_w: pre_w scaled split -> W3
__global__ __launch_bounds__(256) void k_prep(const float* __restrict__ cb,
                                              const float* __restrict__ post_w,
                                              const float* __restrict__ post_b,
                                              const float* __restrict__ pre_w,
                                              float* __restrict__ postcode,
                                              _Float16* __restrict__ B3,
                                              float* __restrict__ csq,
                                              _Float16* __restrict__ W3) {
    __shared__ float smem[4352];              // 17 KB union
    const int bid = blockIdx.x;
    const int tid = threadIdx.x;

    if (bid < 256) {
        // ---------------- postcode ----------------
        float (*cbs)[EMB_] = (float(*)[EMB_])smem;          // [16][256]
        int v0 = bid * 16;
        int c  = tid;
#pragma unroll
        for (int r = 0; r < 16; ++r)
            cbs[r][c] = cb[(v0 + r) * EMB_ + c];
        __syncthreads();
        float acc[16];
        float bias = post_b[c];
#pragma unroll
        for (int r = 0; r < 16; ++r) acc[r] = bias;
        const float4* w4p = (const float4*)(post_w + c * EMB_);
        for (int e4 = 0; e4 < 64; ++e4) {
            float4 w4 = w4p[e4];
#pragma unroll
            for (int r = 0; r < 16; ++r) {
                float4 c4 = *(const float4*)&cbs[r][e4 * 4];
                acc[r] = fmaf(w4.x, c4.x, fmaf(w4.y, c4.y,
                         fmaf(w4.z, c4.z, fmaf(w4.w, c4.w, acc[r]))));
            }
        }
#pragma unroll
        for (int r = 0; r < 16; ++r)
            postcode[(v0 + r) * CCH + c] = acc[r];
    } else if (bid < 512) {
        // ---------------- prep_c ----------------
        float (*cs)[17] = (float(*)[17])smem;               // [256][17]
        int vg = bid - 256;
        int vr = tid >> 4, e0 = (tid & 15) << 4;
        const float* cp = cb + (vg * 16 + vr) * EMB_ + e0;
#pragma unroll
        for (int j = 0; j < 16; ++j)
            cs[e0 + j][vr] = cp[j];
        __syncthreads();
#pragma unroll
        for (int it = 0; it < 4; ++it) {
            int c = it * 256 + tid;
            int kc8 = c >> 4, row = c & 15;
            int lo = kc8 >> 5;
            int kh = kc8 & 31;
            f16x8 outv;
#pragma unroll
            for (int j = 0; j < 8; ++j) {
                float v = cs[kh * 8 + j][row] * 65536.0f;   // exact 2^16 scale
                _Float16 h = (_Float16)v;
                if (lo) h = (_Float16)(v - (float)h);
                outv[j] = h;
            }
            *(f16x8*)(B3 + ((vg * 64 + kc8) * 128 + row * 8)) = outv;
        }
    } else if (bid < 528) {
        // ---------------- csq ----------------
        int v = (bid - 512) * 256 + tid;
        const float4* row = (const float4*)(cb + v * EMB_);
        float s = 0.f;
#pragma unroll 8
        for (int q = 0; q < 64; ++q) {
            float4 a = row[q];
            s = fmaf(a.x, a.x, fmaf(a.y, a.y, fmaf(a.z, a.z, fmaf(a.w, a.w, s))));
        }
        csq[v] = s;
    } else {
        // ---------------- prep_w: scaled split of pre_w ----------------
        int eg = bid - 528;                   // 0..15
#pragma unroll
        for (int i = 0; i < 4; ++i) {
            int flat = i * 256 + tid;         // 0..1023 = [u64][row16]
            int u = flat >> 4, row = flat & 15;
            int part = u >> 5, c8 = u & 31;
            const float* wp = pre_w + (eg * 16 + row) * CCH + c8 * 8;
            f16x8 outv;
#pragma unroll
            for (int j = 0; j < 8; ++j) {
                float v = wp[j] * 16.0f;                    // exact 2^4 scale
                _Float16 h = (_Float16)v;
                if (part) h = (_Float16)((v - (float)h) * 4096.0f); // exact*2^12, RN
                outv[j] = h;
            }
            *(f16x8*)(W3 + ((eg * 64 + u) * 128 + row * 8)) = outv;
        }
    }
}

// ============ K1: z-GEMM on MFMA (unchanged from R6) =======================
__global__ __launch_bounds__(512) void k_zgemm(const float* __restrict__ x,
                                               const _Float16* __restrict__ W3,
                                               const float* __restrict__ pre_b,
                                               float* __restrict__ zout,
                                               _Float16* __restrict__ A3) {
    __shared__ __align__(16) char smem[99328];
    float* pbs = (float*)(smem + 98304);

    const int tid = threadIdx.x;
    const int l   = tid & 63;
    const int w   = tid >> 6;
    const int l15 = l & 15, l4 = l >> 4;
    const int wr  = w >> 2, wc = w & 3;
    const int bM  = blockIdx.x;
    const int b   = bM >> 1, hw0 = (bM & 1) * 128;

    const int xng = tid >> 6, xu = (tid >> 4) & 3, xrow = tid & 15;
    const float* xbase = x + (size_t)b * (CCH * HW) + hw0 + xng * 16 + xrow;

#define STAGE_W(CC, BUF) {                                                   \
    _Pragma("unroll")                                                        \
    for (int i = 0; i < 2; ++i) {                                            \
        int flat = i * 512 + tid; int eg = flat >> 6, sub = flat & 63;       \
        async16((_Float16*)(smem + (BUF) * 16384) + flat * 8,                \
                W3 + (eg * 64 + (CC) * 4) * 128 + sub * 8);                  \
        async16((_Float16*)(smem + 32768 + (BUF) * 16384) + flat * 8,        \
                W3 + (eg * 64 + 32 + (CC) * 4) * 128 + sub * 8);             \
    } }

#define STAGE_X(CC, BUF) {                                                   \
    const float* xp_ = xbase + ((CC) * 32 + xu * 8) * HW;                    \
    f16x8 hv, lv;                                                            \
    _Pragma("unroll")                                                        \
    for (int j = 0; j < 8; ++j) {                                            \
        float xv = 2.0f * xp_[j * HW] - 1.0f;        /* exact */             \
        _Float16 h = (_Float16)xv;                                           \
        lv[j] = (_Float16)((xv - (float)h) * 4096.0f); /* exact*2^12, RN */  \
        hv[j] = h;                                                           \
    }                                                                        \
    *(f16x8*)((_Float16*)(smem + 65536 + (BUF) * 8192) + tid * 8) = hv;      \
    *(f16x8*)((_Float16*)(smem + 81920 + (BUF) * 8192) + tid * 8) = lv;      \
    }

    if (tid < 256) pbs[tid] = pre_b[tid];
    STAGE_W(0, 0)
    STAGE_X(0, 0)
    __syncthreads();

    f32x4 accA[4][4], accB[4][4];
    const f32x4 zero4 = {0.f, 0.f, 0.f, 0.f};
#pragma unroll
    for (int m = 0; m < 4; ++m)
#pragma unroll
        for (int s = 0; s < 4; ++s) { accA[m][s] = zero4; accB[m][s] = zero4; }

    int buf = 0;
    for (int cc = 0; cc < 8; ++cc) {
        if (cc < 7) { STAGE_W(cc + 1, buf ^ 1) STAGE_X(cc + 1, buf ^ 1) }
        const _Float16* WhC = (const _Float16*)(smem + buf * 16384);
        const _Float16* WlC = (const _Float16*)(smem + 32768 + buf * 16384);
        const _Float16* XhC = (const _Float16*)(smem + 65536 + buf * 8192);
        const _Float16* XlC = (const _Float16*)(smem + 81920 + buf * 8192);
        f16x8 whf[4], wlf[4], xhf[4], xlf[4];
#pragma unroll
        for (int m = 0; m < 4; ++m) {
            whf[m] = *(const f16x8*)&WhC[((wc * 4 + m) * 64 + l4 * 16 + l15) * 8];
            wlf[m] = *(const f16x8*)&WlC[((wc * 4 + m) * 64 + l4 * 16 + l15) * 8];
        }
#pragma unroll
        for (int s = 0; s < 4; ++s) {
            xhf[s] = *(const f16x8*)&XhC[((wr * 4 + s) * 64 + l4 * 16 + l15) * 8];
            xlf[s] = *(const f16x8*)&XlC[((wr * 4 + s) * 64 + l4 * 16 + l15) * 8];
        }
#pragma unroll
        for (int m = 0; m < 4; ++m)
#pragma unroll
            for (int s = 0; s < 4; ++s)
                accA[m][s] = __builtin_amdgcn_mfma_f32_16x16x32_f16(whf[m], xhf[s], accA[m][s], 0, 0, 0);
#pragma unroll
        for (int m = 0; m < 4; ++m)
#pragma unroll
            for (int s = 0; s < 4; ++s)
                accB[m][s] = __builtin_amdgcn_mfma_f32_16x16x32_f16(whf[m], xlf[s], accB[m][s], 0, 0, 0);
#pragma unroll
        for (int m = 0; m < 4; ++m)
#pragma unroll
            for (int s = 0; s < 4; ++s)
                accB[m][s] = __builtin_amdgcn_mfma_f32_16x16x32_f16(wlf[m], xhf[s], accB[m][s], 0, 0, 0);
        __syncthreads();
        buf ^= 1;
    }

    // ---- epilogue: z = combine + bias; store z_out; pack A3 (per-wave LDS)
    float* zw = (float*)(smem + w * 5120);    // [64 n][20 floats] this wave
    const size_t zbase = (size_t)b * (EMB_ * HW) + hw0;
#pragma unroll
    for (int m = 0; m < 4; ++m) {
        asm volatile("s_waitcnt lgkmcnt(0)" ::: "memory");   // prev pack reads done
        __builtin_amdgcn_sched_barrier(0);
        f32x4 zv[4];
#pragma unroll
        for (int s = 0; s < 4; ++s) {
#pragma unroll
            for (int r = 0; r < 4; ++r) {
                float g = fmaf(accB[m][s][r], 0x1p-12f, accA[m][s][r]) * 0x1p-4f;
                zv[s][r] = g + pbs[wc * 64 + m * 16 + l4 * 4 + r];
            }
            *(f32x4*)(zw + (s * 16 + l15) * 20 + l4 * 4) = zv[s];
#pragma unroll
            for (int r = 0; r < 4; ++r)
                zout[zbase + (size_t)(wc * 64 + m * 16 + l4 * 4 + r) * HW
                     + wr * 64 + s * 16 + l15] = zv[s][r];
        }
        asm volatile("s_waitcnt lgkmcnt(0)" ::: "memory");   // zbuf writes visible
        __builtin_amdgcn_sched_barrier(0);
#pragma unroll
        for (int o = 0; o < 4; ++o) {
            int flat = o * 64 + l;
            int part = flat >> 7, rest = flat & 127;
            int pg = rest >> 5, uq = (rest >> 4) & 1, row = rest & 15;
            int nloc = pg * 16 + row;
            float4 va = *(const float4*)(zw + nloc * 20 + uq * 8);
            float4 vb = *(const float4*)(zw + nloc * 20 + uq * 8 + 4);
            float vs[8] = {va.x, va.y, va.z, va.w, vb.x, vb.y, vb.z, vb.w};
            f16x8 outv;
#pragma unroll
            for (int j = 0; j < 8; ++j) {
                float v = vs[j] * 256.0f;                    // exact 2^8 scale
                _Float16 h = (_Float16)v;
                if (part) h = (_Float16)(v - (float)h);      // exact residual, RN
                outv[j] = h;
            }
            *(f16x8*)(A3 + ((size_t)(bM * 8 + wr * 4 + pg) * 64
                            + part * 32 + wc * 8 + m * 2 + uq) * 128 + row * 8) = outv;
        }
    }
#undef STAGE_W
#undef STAGE_X
}

// --------- K2 staging: BK=32 chunk = 4 contiguous kc8 units at offset kA/kB.
__device__ __forceinline__ void issueA(const _Float16* __restrict__ A3, int bM,
                                       int w, int l, _Float16* dst, int kA) {
#pragma unroll
    for (int i = 0; i < 2; ++i) {
        int pg = 2 * w + i;                           // pixel-group 0..15
        const _Float16* g = A3 + ((bM * 16 + pg) * 64 + kA) * 128 + l * 8;
        async16(dst + pg * 512, g);                   // linear both sides
    }
}

__device__ __forceinline__ void issueB(const _Float16* __restrict__ B3, int vgbase,
                                       int w, int l, _Float16* dst, int kB) {
#pragma unroll
    for (int i = 0; i < 2; ++i) {
        int vg = 2 * w + i;                           // code-group 0..15
        const _Float16* g = B3 + ((vgbase + vg) * 64 + kB) * 128 + l * 8;
        async16(dst + vg * 512, g);
    }
}

// --------------------------------- K2: MFMA distance GEMM + fused argmin
// R4 structure, prefetch depth 2 -> 3 (4 LDS buffers, vmcnt(8) steady state).
// MFMA k-order identical -> tokens bit-identical.
__global__ __launch_bounds__(512) void k_dist(const float* __restrict__ zout,
                                              const _Float16* __restrict__ A3,
                                              const _Float16* __restrict__ B3,
                                              const float* __restrict__ csq,
                                              float* __restrict__ bestw,
                                              int* __restrict__ bidxw) {
    __shared__ __align__(16) _Float16 Ab[4][8192];    // 64 KB (16 KB/chunk)
    __shared__ __align__(16) _Float16 Bb[4][8192];    // 64 KB
    __shared__ float csq_s[2048];                     // 8 KB (this half only)
    __shared__ float zsq_s[256];
    __shared__ float red_b[8][128];
    __shared__ int   red_i[8][128];

    const int tid = threadIdx.x;
    const int l   = tid & 63;
    const int w   = tid >> 6;
    const int l15 = l & 15, l4 = l >> 4;
    const int wr  = w >> 2, wc = w & 3;               // 2M x 4N wave grid
    const int bM  = blockIdx.x & 127;                 // M-tile (256 pixels)
    const int nh  = blockIdx.x >> 7;                  // code half 0/1
    const int vgb = nh * 128;                         // B3 group base

    // kA(kc) = (kc>=16 ? 32:0) + (kc&7)*4 ; kB(kc) = (8<=kc<16 ? 32:0) + (kc&7)*4
    // prologue: stage chunks 0,1,2
    issueA(A3, bM, w, l, Ab[0], 0);  issueB(B3, vgb, w, l, Bb[0], 0);
    issueA(A3, bM, w, l, Ab[1], 4);  issueB(B3, vgb, w, l, Bb[1], 4);
    issueA(A3, bM, w, l, Ab[2], 8);  issueB(B3, vgb, w, l, Bb[2], 8);

    // csq half -> LDS
#pragma unroll
    for (int j = 0; j < 4; ++j) csq_s[j * 512 + tid] = csq[nh * 2048 + j * 512 + tid];

    // zsq: serial fmaf chain over e (identical rounding to passing kernel)
    if (tid < 256) {
        const float* zp = zout + bM * (EMB_ * HW) + tid;
        float s = 0.f;
        for (int k = 0; k < 256; ++k) { float zv = zp[k * HW]; s = fmaf(zv, zv, s); }
        zsq_s[tid] = s;
    }
    __syncthreads();   // one-time full drain: chunks 0-2 + csq_s + zsq_s ready

    float best[32]; int bidx[32];
#pragma unroll
    for (int i = 0; i < 32; ++i) { best[i] = FLT_MAX; bidx[i] = 0; }

    const f32x4 zero4 = {0.f, 0.f, 0.f, 0.f};
    int cur = 0;
    for (int vt = 0; vt < 8; ++vt) {
        f32x4 acc[8][4];
#pragma unroll
        for (int s = 0; s < 8; ++s)
#pragma unroll
            for (int m = 0; m < 4; ++m) acc[s][m] = zero4;

        for (int kc = 0; kc < 24; ++kc) {
            const int n = vt * 24 + kc;               // global chunk 0..191
            int kc3 = kc + 3, vt3 = vt;
            if (kc3 >= 24) { kc3 -= 24; ++vt3; }
            const int nxt = (cur + 3) & 3;
            const bool pf = (vt3 < 8);
            const int kA3 = ((kc3 >= 16) ? 32 : 0) + (kc3 & 7) * 4;
            const int kB3 = ((kc3 >= 8 && kc3 < 16) ? 32 : 0) + (kc3 & 7) * 4;

            // ---------------- phase 0: s-half 0 ----------------
            f16x8 af0[4], bf[4];
#pragma unroll
            for (int s = 0; s < 4; ++s)
                af0[s] = *(const f16x8*)&Ab[cur][(wr * 8 + s) * 512 + l4 * 128 + l15 * 8];
#pragma unroll
            for (int m = 0; m < 4; ++m)
                bf[m] = *(const f16x8*)&Bb[cur][(wc * 4 + m) * 512 + l4 * 128 + l15 * 8];
            if (pf) issueA(A3, bM, w, l, Ab[nxt], kA3);
            __builtin_amdgcn_s_barrier();
            asm volatile("s_waitcnt lgkmcnt(0)" ::: "memory");
            __builtin_amdgcn_sched_barrier(0);
            __builtin_amdgcn_s_setprio(1);
#pragma unroll
            for (int s = 0; s < 4; ++s)
#pragma unroll
                for (int m = 0; m < 4; ++m)
                    acc[s][m] = __builtin_amdgcn_mfma_f32_16x16x32_f16(af0[s], bf[m], acc[s][m], 0, 0, 0);
            __builtin_amdgcn_s_setprio(0);
            __builtin_amdgcn_s_barrier();

            // ---------------- phase 1: s-half 1 ----------------
            f16x8 af1[4];
#pragma unroll
            for (int s = 0; s < 4; ++s)
                af1[s] = *(const f16x8*)&Ab[cur][(wr * 8 + 4 + s) * 512 + l4 * 128 + l15 * 8];
            if (pf) issueB(B3, vgb + vt3 * 16, w, l, Bb[nxt], kB3);
            __builtin_amdgcn_s_barrier();
            asm volatile("s_waitcnt lgkmcnt(0)" ::: "memory");
            __builtin_amdgcn_sched_barrier(0);
            __builtin_amdgcn_s_setprio(1);
#pragma unroll
            for (int s = 0; s < 4; ++s)
#pragma unroll
                for (int m = 0; m < 4; ++m)
                    acc[4 + s][m] = __builtin_amdgcn_mfma_f32_16x16x32_f16(af1[s], bf[m], acc[4 + s][m], 0, 0, 0);
            __builtin_amdgcn_s_setprio(0);
            // counted drain: chunk n+1 must be in LDS; n+2,n+3 stay in flight.
            // outstanding at this point: (n+1,n+2,n+3 issued) = 12 loads.
            if (n <= 188)      { asm volatile("s_waitcnt vmcnt(8)" ::: "memory"); }
            else if (n == 189) { asm volatile("s_waitcnt vmcnt(4)" ::: "memory"); }
            else               { asm volatile("s_waitcnt vmcnt(0)" ::: "memory"); }
            __builtin_amdgcn_s_barrier();
            __builtin_amdgcn_sched_barrier(0);
            cur = (cur + 1) & 3;
        }

        // ---- fold tile into running argmin (codes ascending per slot)
#pragma unroll
        for (int m = 0; m < 4; ++m) {
            int cl = vt * 256 + (wc * 4 + m) * 16 + l15;   // half-local code
            float cs = csq_s[cl];
            int code = nh * 2048 + cl;
#pragma unroll
            for (int s = 0; s < 8; ++s)
#pragma unroll
                for (int r = 0; r < 4; ++r) {
                    float dd = (zsq_s[wr * 128 + s * 16 + l4 * 4 + r] + cs)
                               - acc[s][m][r] * 0x1p-23f;
                    int pi = s * 4 + r;
                    if (dd < best[pi]) { best[pi] = dd; bidx[pi] = code; }
                }
        }
    }

    // reduce over the 16 code-columns (l15 dimension) lexicographically
#pragma unroll
    for (int off = 8; off >= 1; off >>= 1) {
#pragma unroll
        for (int i = 0; i < 32; ++i) {
            float ob = __shfl_xor(best[i], off, 64);
            int   oi = __shfl_xor(bidx[i], off, 64);
            if (ob < best[i] || (ob == best[i] && oi < bidx[i])) { best[i] = ob; bidx[i] = oi; }
        }
    }
    if (l15 == 0) {
#pragma unroll
        for (int s = 0; s < 8; ++s)
#pragma unroll
            for (int r = 0; r < 4; ++r) {
                int pl = s * 16 + l4 * 4 + r;             // wave-local pixel
                red_b[w][pl] = best[s * 4 + r];
                red_i[w][pl] = bidx[s * 4 + r];
            }
    }
    __syncthreads();
    // combine the 4 code-quarter waves (same wr) per pixel, store (best,idx)
    if (tid < 256) {
        int wrg = tid >> 7, pl = tid & 127;
        float bb = red_b[wrg * 4][pl]; int bi = red_i[wrg * 4][pl];
#pragma unroll
        for (int c = 1; c < 4; ++c) {
            float ob = red_b[wrg * 4 + c][pl]; int oi = red_i[wrg * 4 + c][pl];
            if (ob < bb || (ob == bb && oi < bi)) { bb = ob; bi = oi; }
        }
        bestw[nh * NPIX + bM * 256 + tid] = bb;
        bidxw[nh * NPIX + bM * 256 + tid] = bi;
    }
}

// ---------------- K2b: combine halves (fallback path only)
__global__ __launch_bounds__(256) void k_argmin2(const float* __restrict__ bestw,
                                                 const int* __restrict__ bidxw,
                                                 float* __restrict__ tok_f) {
    int i = blockIdx.x * 256 + threadIdx.x;   // grid 128
    float b0 = bestw[i], b1 = bestw[NPIX + i];
    int   i0 = bidxw[i], i1 = bidxw[NPIX + i];
    tok_f[i] = (float)((b1 < b0) ? i1 : i0);  // half-0 wins ties (lower idx)
}

// ------------------------- K3: gather (fallback path only)
__global__ __launch_bounds__(256) void k_gather(const float* __restrict__ tok_f,
                                                const float* __restrict__ cb,
                                                const float* __restrict__ postcode,
                                                float* __restrict__ zq_out,
                                                float* __restrict__ recon) {
    int b  = blockIdx.x >> 3;                 // grid 1024
    int e0 = (blockIdx.x & 7) * 32;
    int hw = threadIdx.x;
    int t  = (int)tok_f[b * HW + hw];
    const float* cbr = cb       + t * EMB_;
    const float* pcr = postcode + t * CCH;
    float* zq = zq_out + b * (EMB_ * HW) + hw;
    float* rc = recon  + b * (CCH * HW) + hw;
#pragma unroll
    for (int j = 0; j < 32; ++j) {
        int e = e0 + j;
        zq[e * HW] = cbr[e];
        rc[e * HW] = pcr[e];
    }
}

// ---- K3t: LDS-transposed gather: coalesced row reads + coalesced hw writes.
// Grid 256 = (b 128) x (px-half 2), 256 threads. Per 64-px group: compute
// tokens, stage 64 codebook rows coalesced (1KB rows), write out hw-major
// (lanes = pixel, 256B contiguous); repeat for postcode rows reusing LDS.
// [64][257] padding -> bank (p+e)%32, 2-way on writes-out = free.
__global__ __launch_bounds__(256) void k_gather2(const float* __restrict__ bestw,
                                                 const int* __restrict__ bidxw,
                                                 const float* __restrict__ cb,
                                                 const float* __restrict__ postcode,
                                                 float* __restrict__ zq_out,
                                                 float* __restrict__ recon,
                                                 float* __restrict__ tok_f) {
    __shared__ float rows[64][257];           // 64.25 KB
    __shared__ int   toks[64];
    const int b    = blockIdx.x >> 1;
    const int half = blockIdx.x & 1;
    const int tid  = threadIdx.x;
    const int p    = tid & 63, eg = tid >> 6;

    for (int g = 0; g < 2; ++g) {
        int px0 = half * 128 + g * 64;
        if (tid < 64) {
            int i = b * HW + px0 + tid;
            float b0 = bestw[i], b1 = bestw[NPIX + i];
            int   i0 = bidxw[i], i1 = bidxw[NPIX + i];
            int t = (b1 < b0) ? i1 : i0;      // identical to k_argmin2
            toks[tid] = t;
            tok_f[i] = (float)t;
        }
        __syncthreads();
        // ---- codebook pass ----
#pragma unroll 8
        for (int r = 0; r < 64; ++r)
            rows[r][tid] = cb[(size_t)toks[r] * EMB_ + tid];   // coalesced 1KB
        __syncthreads();
        {
            float* zq = zq_out + (size_t)b * (EMB_ * HW) + px0 + p;
#pragma unroll 8
            for (int eo = 0; eo < 64; ++eo) {
                int e = eg * 64 + eo;
                zq[(size_t)e * HW] = rows[p][e];               // 256B contiguous
            }
        }
        __syncthreads();
        // ---- postcode pass (reuse rows) ----
#pragma unroll 8
        for (int r = 0; r < 64; ++r)
            rows[r][tid] = postcode[(size_t)toks[r] * CCH + tid];
        __syncthreads();
        {
            float* rc = recon + (size_t)b * (CCH * HW) + px0 + p;
#pragma unroll 8
            for (int eo = 0; eo < 64; ++eo) {
                int e = eg * 64 + eo;
                rc[(size_t)e * HW] = rows[p][e];
            }
        }
        __syncthreads();                       // before next group reuses LDS
    }
}

extern "C" void kernel_launch(void* const* d_in, const int* in_sizes, int n_in,
                              void* d_out, int out_size, void* d_ws, size_t ws_size,
                              hipStream_t stream) {
    const float* x      = (const float*)d_in[0];
    const float* cb     = (const float*)d_in[1];
    const float* pre_w  = (const float*)d_in[2];
    const float* pre_b  = (const float*)d_in[3];
    const float* post_w = (const float*)d_in[4];
    const float* post_b = (const float*)d_in[5];

    float* out    = (float*)d_out;
    float* z_out  = out;                       //  8388608 elems
    float* zq_out = out + 8388608;             //  8388608
    float* recon  = out + 16777216;            //  8388608
    float* tok_f  = out + 25165824;            //    32768

    _Float16* A3 = (_Float16*)zq_out;          // [2048][64][16][8] fp16
    _Float16* B3 = (_Float16*)recon;           // [256][64][16][8]  fp16
    _Float16* W3 = (_Float16*)(recon + 1048576 + 4 * NPIX);  // 131072 f16

    float* csq      = (float*)d_ws;            // 4096 floats
    float* postcode = csq + VOC;               // 4096*256 floats (4 MB)

    size_t need = (size_t)(VOC + VOC * CCH + 4 * NPIX) * sizeof(float);
    bool fused = (ws_size >= need);
    float* bestw; int* bidxw;
    if (fused) {
        bestw = postcode + (size_t)VOC * CCH;  // 2*NPIX floats
        bidxw = (int*)(bestw + 2 * NPIX);      // 2*NPIX ints
    } else {
        bestw = recon + 1048576;
        bidxw = (int*)(recon + 1048576 + 2 * NPIX);
    }

    k_prep <<< 544, 256, 0, stream>>>(cb, post_w, post_b, pre_w,
                                      postcode, B3, csq, W3);
    k_zgemm<<< 256, 512, 0, stream>>>(x, W3, pre_b, z_out, A3);
    k_dist <<< 256, 512, 0, stream>>>(z_out, A3, B3, csq, bestw, bidxw);
    if (fused) {
        k_gather2<<< 256, 256, 0, stream>>>(bestw, bidxw, cb, postcode,
                                            zq_out, recon, tok_f);
    } else {
        k_argmin2<<< 128, 256, 0, stream>>>(bestw, bidxw, tok_f);
        k_gather <<<1024, 256, 0, stream>>>(tok_f, cb, postcode, zq_out, recon);
    }
}